// Round 11
// baseline (750.500 us; speedup 1.0000x reference)
//
#include <hip/hip_runtime.h>
#include <math.h>

#define HH 192
#define WW 192
#define HWP (192*192)
#define BB 4
#define CF 64
#define NC 7
#define OO 64
#define NTOT (BB*HWP)          // 147456
#define PIX_BLOCKS (HWP/256)   // 144
#define PBLK2 (HWP/128)        // 288 (attn/final gemm blocks per batch)

typedef float f32x16 __attribute__((ext_vector_type(16)));
typedef float f32x4  __attribute__((ext_vector_type(4)));

// ---------------- vectorized depthwise conv: 4 outputs/thread -------------
template<int k>
__global__ __launch_bounds__(256)
void dwv_kernel(const float* __restrict__ fea, const float* __restrict__ w,
                const float* __restrict__ bias, float* __restrict__ out) {
    constexpr int pad = k / 2;
    int idx = blockIdx.x * 256 + threadIdx.x;      // over B*CF*HH*48
    int xq = idx % 48;
    int x0 = xq * 4;
    int hpos = (idx / 48) % HH;
    int plane = idx / (48 * HH);                   // uniform per block
    int c = plane % CF;
    const float* f = fea + (size_t)plane * HWP;

    float wk[k * k];
#pragma unroll
    for (int i = 0; i < k * k; ++i) wk[i] = w[c * k * k + i];

    float acc0 = 0.f, acc1 = 0.f, acc2 = 0.f, acc3 = 0.f;
#pragma unroll
    for (int dy = 0; dy < k; ++dy) {
        int y = hpos + dy - pad;
        if (y < 0 || y >= HH) continue;
        const float* row = f + y * WW;
        float4 q0 = (x0 >= 4) ? *(const float4*)(row + x0 - 4) : make_float4(0.f, 0.f, 0.f, 0.f);
        float4 q1 = *(const float4*)(row + x0);
        float4 q2 = (x0 + 4 < WW) ? *(const float4*)(row + x0 + 4) : make_float4(0.f, 0.f, 0.f, 0.f);
        float wnd[8] = {q0.z, q0.w, q1.x, q1.y, q1.z, q1.w, q2.x, q2.y};
#pragma unroll
        for (int dx = 0; dx < k; ++dx) {
            float wt = wk[dy * k + dx];
            acc0 += wnd[0 + dx + 2 - pad] * wt;
            acc1 += wnd[1 + dx + 2 - pad] * wt;
            acc2 += wnd[2 + dx + 2 - pad] * wt;
            acc3 += wnd[3 + dx + 2 - pad] * wt;
        }
    }
    float b = bias[c];
    float4 o = make_float4(acc0 + b, acc1 + b, acc2 + b, acc3 + b);
    *(float4*)(out + (size_t)plane * HWP + hpos * WW + x0) = o;
}

// ---------------- generic small transpose ----------------
__global__ void transpose_kernel(const float* __restrict__ in, float* __restrict__ out,
                                 int rows, int cols) {
    int idx = blockIdx.x * 256 + threadIdx.x;
    if (idx >= rows * cols) return;
    int r = idx / cols, c = idx % cols;
    out[c * rows + r] = in[idx];
}

// ---------------- pw GEMM: om[m][NTOT] = pw_w[src(m)][:] @ dw + pw_b -------
__global__ __launch_bounds__(256)
void pw_gemm_kernel(const float* __restrict__ pw_w, const float* __restrict__ pw_b,
                    const float* __restrict__ dw, float* __restrict__ om,
                    int src0, int n_yx, int src1, int M) {
    __shared__ float As[64][68];
    __shared__ float Bs[64][132];
    const int ntiles = NTOT / 128;
    int ntile = blockIdx.x % ntiles;
    int mtile = blockIdx.x / ntiles;
    int nb0 = ntile * 128;
    int mb0 = mtile * 64;
    int tid = threadIdx.x;

    {
        int m = tid & 63;
        int kq = tid >> 6;
        int gm = mb0 + m;
        int srow = (gm < M) ? ((gm < n_yx) ? (src0 + gm) : (src1 + (gm - n_yx))) : src0;
        const float* ap = pw_w + (size_t)srow * CF;
#pragma unroll
        for (int i = 0; i < 4; ++i) {
            int k0 = (kq * 4 + i) * 4;
            float4 v = *(const float4*)(ap + k0);
            As[k0 + 0][m] = v.x; As[k0 + 1][m] = v.y;
            As[k0 + 2][m] = v.z; As[k0 + 3][m] = v.w;
        }
    }
    {
        int b = nb0 / HWP;
        int p0 = nb0 % HWP;
        const float* bp = dw + (size_t)b * CF * HWP + p0;
#pragma unroll
        for (int i = 0; i < 8; ++i) {
            int idx = tid + i * 256;
            int kk = idx >> 5;
            int f4 = idx & 31;
            float4 v = *(const float4*)(bp + (size_t)kk * HWP + f4 * 4);
            *(float4*)&Bs[kk][f4 * 4] = v;
        }
    }
    __syncthreads();

    int tm = (tid & 15) * 4;
    int tn = (tid >> 4) * 8;
    f32x4 aA0 = 0.f, aA1 = 0.f, aB0 = 0.f, aB1 = 0.f;
    f32x4 aC0 = 0.f, aC1 = 0.f, aD0 = 0.f, aD1 = 0.f;
#pragma unroll 8
    for (int kk = 0; kk < 64; ++kk) {
        f32x4 a  = *(const f32x4*)&As[kk][tm];
        f32x4 b0 = *(const f32x4*)&Bs[kk][tn];
        f32x4 b1 = *(const f32x4*)&Bs[kk][tn + 4];
#pragma unroll
        for (int j = 0; j < 4; ++j) {
            aA0[j] += a[0] * b0[j];  aA1[j] += a[0] * b1[j];
            aB0[j] += a[1] * b0[j];  aB1[j] += a[1] * b1[j];
            aC0[j] += a[2] * b0[j];  aC1[j] += a[2] * b1[j];
            aD0[j] += a[3] * b0[j];  aD1[j] += a[3] * b1[j];
        }
    }
    {
        int gm = mb0 + tm;
        float* dst = om + (size_t)gm * NTOT + nb0 + tn;
        if (gm < M) {
            float bi = pw_b[(gm < n_yx) ? (src0 + gm) : (src1 + gm - n_yx)];
#pragma unroll
            for (int j = 0; j < 4; ++j) { dst[j] = aA0[j] + bi; dst[4 + j] = aA1[j] + bi; }
        }
        gm++; dst += NTOT;
        if (gm < M) {
            float bi = pw_b[(gm < n_yx) ? (src0 + gm) : (src1 + gm - n_yx)];
#pragma unroll
            for (int j = 0; j < 4; ++j) { dst[j] = aB0[j] + bi; dst[4 + j] = aB1[j] + bi; }
        }
        gm++; dst += NTOT;
        if (gm < M) {
            float bi = pw_b[(gm < n_yx) ? (src0 + gm) : (src1 + gm - n_yx)];
#pragma unroll
            for (int j = 0; j < 4; ++j) { dst[j] = aC0[j] + bi; dst[4 + j] = aC1[j] + bi; }
        }
        gm++; dst += NTOT;
        if (gm < M) {
            float bi = pw_b[(gm < n_yx) ? (src0 + gm) : (src1 + gm - n_yx)];
#pragma unroll
            for (int j = 0; j < 4; ++j) { dst[j] = aD0[j] + bi; dst[4 + j] = aD1[j] + bi; }
        }
    }
}

// ---------------- sampling only: s[tap][pixel] ----------------------------
template<int k>
__global__ __launch_bounds__(256)
void sample_kernel(const float* __restrict__ om, const float* __restrict__ inputs,
                   float* __restrict__ sbuf, int t0, int t1) {
    constexpr int K = k * k;
    constexpr int pad = k / 2;
    const int T = t1 - t0;
    int g = blockIdx.x / (NTOT / 256);
    int nb = blockIdx.x % (NTOT / 256);
    int n = nb * 256 + threadIdx.x;
    int b = n / HWP, p = n % HWP;
    int h = p / WW, wq = p % WW;
    const float* inb = inputs + (size_t)b * NC * HWP;
    int half = (T + 1) >> 1;
    int i0 = g * half;
    int i1 = min(T, i0 + half);
#pragma unroll 2
    for (int i = i0; i < i1; ++i) {
        int r = t0 + i;
        float oy = om[(size_t)(2 * i) * NTOT + n];
        float ox = om[(size_t)(2 * i + 1) * NTOT + n];
        float mr = om[(size_t)(2 * T + i) * NTOT + n];
        int c = r / K;
        int kk = r - c * K;
        int ky = kk / k, kx = kk - ky * k;
        const float* inc_ = inb + (size_t)c * HWP;
        float m = 1.f / (1.f + __expf(-mr));
        float py = oy + (float)(ky + h - pad);
        float px = ox + (float)(kx + wq - pad);
        float y0 = floorf(py), x0 = floorf(px);
        float wyf = py - y0, wxf = px - x0;
        int iy0 = (int)y0, ix0 = (int)x0;
        bool y0v = (iy0 >= 0) && (iy0 < HH);
        bool y1v = (iy0 + 1 >= 0) && (iy0 + 1 < HH);
        bool x0v = (ix0 >= 0) && (ix0 < WW);
        bool x1v = (ix0 + 1 >= 0) && (ix0 + 1 < WW);
        int yc0 = min(max(iy0, 0), HH - 1), yc1 = min(max(iy0 + 1, 0), HH - 1);
        int xc0 = min(max(ix0, 0), WW - 1), xc1 = min(max(ix0 + 1, 0), WW - 1);
        float v00 = 0.f, v01 = 0.f, v10 = 0.f, v11 = 0.f;
        if (y0v) {
            if (x0v) v00 = inc_[yc0 * WW + xc0];
            if (x1v) v01 = inc_[yc0 * WW + xc1];
        }
        if (y1v) {
            if (x0v) v10 = inc_[yc1 * WW + xc0];
            if (x1v) v11 = inc_[yc1 * WW + xc1];
        }
        float s = (v00 * (1.f - wyf) * (1.f - wxf) + v01 * (1.f - wyf) * wxf +
                   v10 * wyf * (1.f - wxf) + v11 * wyf * wxf) * m;
        sbuf[(size_t)i * NTOT + n] = s;
    }
}

// ---------------- accumulation GEMM: outbuf[64][N] (+)= wt^T @ s ----------
__global__ __launch_bounds__(256)
void acc_gemm_kernel(const float* __restrict__ wt,     // [T_all][64]
                     const float* __restrict__ bias,
                     const float* __restrict__ sbuf,   // [T][NTOT] chunk-local
                     float* __restrict__ outbuf, int t_slot,
                     int t0, int t1, int flags) {
    __shared__ float As[64][68];
    __shared__ float Bs[64][132];
    const int T = t1 - t0;          // <= 64
    int nb0 = blockIdx.x * 128;
    int tid = threadIdx.x;

    for (int i4 = tid; i4 < T * 16; i4 += 256) {
        int row = i4 >> 4, c4 = (i4 & 15) * 4;
        float4 v = *(const float4*)(wt + (size_t)(t0 + row) * OO + c4);
        As[row][c4] = v.x; As[row][c4 + 1] = v.y; As[row][c4 + 2] = v.z; As[row][c4 + 3] = v.w;
    }
    for (int i4 = tid; i4 < T * 32; i4 += 256) {
        int row = i4 >> 5, f4 = (i4 & 31) * 4;
        float4 v = *(const float4*)(sbuf + (size_t)row * NTOT + nb0 + f4);
        *(float4*)&Bs[row][f4] = v;
    }
    __syncthreads();

    int tm = (tid & 15) * 4;   // channel
    int tn = (tid >> 4) * 8;   // pixel
    f32x4 aA0 = 0.f, aA1 = 0.f, aB0 = 0.f, aB1 = 0.f;
    f32x4 aC0 = 0.f, aC1 = 0.f, aD0 = 0.f, aD1 = 0.f;
#pragma unroll 2
    for (int kk = 0; kk < T; ++kk) {
        f32x4 a  = *(const f32x4*)&As[kk][tm];
        f32x4 b0 = *(const f32x4*)&Bs[kk][tn];
        f32x4 b1 = *(const f32x4*)&Bs[kk][tn + 4];
#pragma unroll
        for (int j = 0; j < 4; ++j) {
            aA0[j] += a[0] * b0[j];  aA1[j] += a[0] * b1[j];
            aB0[j] += a[1] * b0[j];  aB1[j] += a[1] * b1[j];
            aC0[j] += a[2] * b0[j];  aC1[j] += a[2] * b1[j];
            aD0[j] += a[3] * b0[j];  aD1[j] += a[3] * b1[j];
        }
    }

    int b = nb0 / HWP, p0 = nb0 % HWP;
    f32x4 accs[8] = {aA0, aA1, aB0, aB1, aC0, aC1, aD0, aD1};
#pragma unroll
    for (int row = 0; row < 4; ++row) {
        int ch = tm + row;
        float* ptr = outbuf + ((size_t)((b * 3 + t_slot) * OO + ch)) * HWP + p0 + tn;
        f32x4 lo = accs[row * 2], hi = accs[row * 2 + 1];
        if (!(flags & 1)) {
            f32x4 o0 = *(const f32x4*)ptr;
            f32x4 o1 = *(const f32x4*)(ptr + 4);
#pragma unroll
            for (int j = 0; j < 4; ++j) { lo[j] += o0[j]; hi[j] += o1[j]; }
        }
        if (flags & 2) {
            float bi = bias[ch];
#pragma unroll
            for (int j = 0; j < 4; ++j) {
                lo[j] += bi; hi[j] += bi;
                lo[j] = lo[j] > 0.f ? lo[j] : 0.f;
                hi[j] = hi[j] > 0.f ? hi[j] : 0.f;
            }
        }
        *(f32x4*)ptr = lo;
        *(f32x4*)(ptr + 4) = hi;
    }
}

// ---------------- k=1 branch: fused elementwise dw + 7-tap deform ---------
__global__ __launch_bounds__(256)
void branch_k1_kernel(const float* __restrict__ fea,
                      const float* __restrict__ dw_w0, const float* __restrict__ dw_b0,
                      const float* __restrict__ pw_w, const float* __restrict__ pw_b,
                      const float* __restrict__ inputs,
                      const float* __restrict__ dcn_wt, const float* __restrict__ dcn_b,
                      float* __restrict__ outbuf) {
    __shared__ float lw[21 * 64];
    for (int i = threadIdx.x; i < 21 * 16; i += 256)
        ((float4*)lw)[i] = ((const float4*)pw_w)[i];
    __syncthreads();
    int gid = blockIdx.x;
    int b = gid / PIX_BLOCKS;
    int p = (gid % PIX_BLOCKS) * 256 + threadIdx.x;
    int h = p / WW, wq = p % WW;
    const float* inb = inputs + (size_t)b * NC * HWP;

    f32x16 dwv0, dwv1, dwv2, dwv3;
    {
        const float* fp = fea + (size_t)(b * CF) * HWP + p;
#pragma unroll
        for (int j = 0; j < 16; ++j) dwv0[j] = fp[(size_t)j * HWP] * dw_w0[j] + dw_b0[j];
#pragma unroll
        for (int j = 0; j < 16; ++j) dwv1[j] = fp[(size_t)(16 + j) * HWP] * dw_w0[16 + j] + dw_b0[16 + j];
#pragma unroll
        for (int j = 0; j < 16; ++j) dwv2[j] = fp[(size_t)(32 + j) * HWP] * dw_w0[32 + j] + dw_b0[32 + j];
#pragma unroll
        for (int j = 0; j < 16; ++j) dwv3[j] = fp[(size_t)(48 + j) * HWP] * dw_w0[48 + j] + dw_b0[48 + j];
    }
    f32x16 acc0, acc1, acc2, acc3;
#pragma unroll
    for (int j = 0; j < 16; ++j) { acc0[j] = 0.f; acc1[j] = 0.f; acc2[j] = 0.f; acc3[j] = 0.f; }

    for (int r = 0; r < NC; ++r) {
        const float* wy = lw + (2 * r) * 64;
        const float* wx = wy + 64;
        const float* wm = lw + (14 + r) * 64;
        const float* inc_ = inb + (size_t)r * HWP;
        float oy = pw_b[2 * r], ox = pw_b[2 * r + 1], om = pw_b[14 + r];
#pragma unroll
        for (int j = 0; j < 16; ++j) { oy += wy[j] * dwv0[j];      ox += wx[j] * dwv0[j];      om += wm[j] * dwv0[j]; }
#pragma unroll
        for (int j = 0; j < 16; ++j) { oy += wy[16 + j] * dwv1[j]; ox += wx[16 + j] * dwv1[j]; om += wm[16 + j] * dwv1[j]; }
#pragma unroll
        for (int j = 0; j < 16; ++j) { oy += wy[32 + j] * dwv2[j]; ox += wx[32 + j] * dwv2[j]; om += wm[32 + j] * dwv2[j]; }
#pragma unroll
        for (int j = 0; j < 16; ++j) { oy += wy[48 + j] * dwv3[j]; ox += wx[48 + j] * dwv3[j]; om += wm[48 + j] * dwv3[j]; }
        float m = 1.f / (1.f + __expf(-om));
        float py = oy + (float)h;
        float px = ox + (float)wq;
        float y0 = floorf(py), x0 = floorf(px);
        float wyf = py - y0, wxf = px - x0;
        int iy0 = (int)y0, ix0 = (int)x0;
        bool y0v = (iy0 >= 0) && (iy0 < HH);
        bool y1v = (iy0 + 1 >= 0) && (iy0 + 1 < HH);
        bool x0v = (ix0 >= 0) && (ix0 < WW);
        bool x1v = (ix0 + 1 >= 0) && (ix0 + 1 < WW);
        int yc0 = min(max(iy0, 0), HH - 1), yc1 = min(max(iy0 + 1, 0), HH - 1);
        int xc0 = min(max(ix0, 0), WW - 1), xc1 = min(max(ix0 + 1, 0), WW - 1);
        float v00 = 0.f, v01 = 0.f, v10 = 0.f, v11 = 0.f;
        if (y0v) {
            if (x0v) v00 = inc_[yc0 * WW + xc0];
            if (x1v) v01 = inc_[yc0 * WW + xc1];
        }
        if (y1v) {
            if (x0v) v10 = inc_[yc1 * WW + xc0];
            if (x1v) v11 = inc_[yc1 * WW + xc1];
        }
        float s = (v00 * (1.f - wyf) * (1.f - wxf) + v01 * (1.f - wyf) * wxf +
                   v10 * wyf * (1.f - wxf) + v11 * wyf * wxf) * m;
        const float* dt = dcn_wt + (size_t)r * OO;
#pragma unroll
        for (int j = 0; j < 16; ++j) acc0[j] += s * dt[j];
#pragma unroll
        for (int j = 0; j < 16; ++j) acc1[j] += s * dt[16 + j];
#pragma unroll
        for (int j = 0; j < 16; ++j) acc2[j] += s * dt[32 + j];
#pragma unroll
        for (int j = 0; j < 16; ++j) acc3[j] += s * dt[48 + j];
    }
    float* op = outbuf + (size_t)(b * 3 * OO) * HWP + p;
#pragma unroll
    for (int j = 0; j < 16; ++j) { float v = acc0[j] + dcn_b[j];      op[(size_t)j * HWP] = v > 0.f ? v : 0.f; }
#pragma unroll
    for (int j = 0; j < 16; ++j) { float v = acc1[j] + dcn_b[16 + j]; op[(size_t)(16 + j) * HWP] = v > 0.f ? v : 0.f; }
#pragma unroll
    for (int j = 0; j < 16; ++j) { float v = acc2[j] + dcn_b[32 + j]; op[(size_t)(32 + j) * HWP] = v > 0.f ? v : 0.f; }
#pragma unroll
    for (int j = 0; j < 16; ++j) { float v = acc3[j] + dcn_b[48 + j]; op[(size_t)(48 + j) * HWP] = v > 0.f ? v : 0.f; }
}

// ---------------- attention GEMM: relu(attn_wt^T @ outbuf) + pixel-reduce -
// Round-10 lesson: broadcast-FMA attn_sum had no reuse (68us vs 23us floor).
// Tiled GEMM (K=192 in 3 LDS chunks), then relu + in-thread 8-px sum + LDS
// cross-reduce. partial[(b*PBLK2+lb)*64 + ch].
__global__ __launch_bounds__(256)
void attn_gemm_kernel(const float* __restrict__ outbuf, const float* __restrict__ attn_wt,
                      const float* __restrict__ attn_b, float* __restrict__ partial) {
    __shared__ float As[64][68];
    __shared__ float Bs[64][132];
    __shared__ float red[16][68];
    int nb0 = blockIdx.x * 128;
    int b = nb0 / HWP, p0 = nb0 % HWP;
    int tid = threadIdx.x;
    int tm = (tid & 15) * 4;
    int tn = (tid >> 4) * 8;

    f32x4 aA0 = 0.f, aA1 = 0.f, aB0 = 0.f, aB1 = 0.f;
    f32x4 aC0 = 0.f, aC1 = 0.f, aD0 = 0.f, aD1 = 0.f;
    for (int kc = 0; kc < 3; ++kc) {
        for (int i4 = tid; i4 < 64 * 16; i4 += 256) {
            int row = i4 >> 4, c4 = (i4 & 15) * 4;
            float4 v = *(const float4*)(attn_wt + (size_t)(kc * 64 + row) * OO + c4);
            As[row][c4] = v.x; As[row][c4 + 1] = v.y; As[row][c4 + 2] = v.z; As[row][c4 + 3] = v.w;
        }
        const float* bp = outbuf + ((size_t)(b * 192 + kc * 64)) * HWP + p0;
        for (int i4 = tid; i4 < 64 * 32; i4 += 256) {
            int row = i4 >> 5, f4 = (i4 & 31) * 4;
            float4 v = *(const float4*)(bp + (size_t)row * HWP + f4);
            *(float4*)&Bs[row][f4] = v;
        }
        __syncthreads();
#pragma unroll 4
        for (int kk = 0; kk < 64; ++kk) {
            f32x4 a  = *(const f32x4*)&As[kk][tm];
            f32x4 b0 = *(const f32x4*)&Bs[kk][tn];
            f32x4 b1 = *(const f32x4*)&Bs[kk][tn + 4];
#pragma unroll
            for (int j = 0; j < 4; ++j) {
                aA0[j] += a[0] * b0[j];  aA1[j] += a[0] * b1[j];
                aB0[j] += a[1] * b0[j];  aB1[j] += a[1] * b1[j];
                aC0[j] += a[2] * b0[j];  aC1[j] += a[2] * b1[j];
                aD0[j] += a[3] * b0[j];  aD1[j] += a[3] * b1[j];
            }
        }
        __syncthreads();
    }
    // relu + sum over this thread's 8 pixels, per channel
    float bsum[4];
    {
        f32x4 accs[8] = {aA0, aA1, aB0, aB1, aC0, aC1, aD0, aD1};
#pragma unroll
        for (int row = 0; row < 4; ++row) {
            float bi = attn_b[tm + row];
            float s = 0.f;
#pragma unroll
            for (int j = 0; j < 4; ++j) {
                float v0 = accs[row * 2][j] + bi;
                float v1 = accs[row * 2 + 1][j] + bi;
                s += (v0 > 0.f ? v0 : 0.f) + (v1 > 0.f ? v1 : 0.f);
            }
            bsum[row] = s;
        }
    }
    int pg = tid >> 4;   // pixel group 0..15
#pragma unroll
    for (int row = 0; row < 4; ++row) red[pg][tm + row] = bsum[row];
    __syncthreads();
    if (tid < 64) {
        float s = 0.f;
#pragma unroll
        for (int g = 0; g < 16; ++g) s += red[g][tid];
        int lb = p0 / 128;
        partial[((size_t)(b * PBLK2 + lb)) * OO + tid] = s;
    }
}

// ---------------- attention finish ----------------
__global__ void attn_finish_kernel(const float* __restrict__ partial,
                                   const float* __restrict__ fc_w, const float* __restrict__ fc_b,
                                   const float* __restrict__ fcs_w0, const float* __restrict__ fcs_b0,
                                   const float* __restrict__ fcs_w1, const float* __restrict__ fcs_b1,
                                   const float* __restrict__ fcs_w2, const float* __restrict__ fcs_b2,
                                   float* __restrict__ atts) {
    int b = blockIdx.x;
    __shared__ float attm[OO];
    __shared__ float fcv[32];
    int tid = threadIdx.x;
    if (tid < OO) {
        float s = 0.f;
        for (int blk = 0; blk < PBLK2; ++blk)
            s += partial[((size_t)(b * PBLK2 + blk)) * OO + tid];
        attm[tid] = s / (float)HWP;
    }
    __syncthreads();
    if (tid < 32) {
        float s = fc_b[tid];
        for (int o = 0; o < OO; ++o) s += fc_w[tid * OO + o] * attm[o];
        fcv[tid] = s > 0.f ? s : 0.f;
    }
    __syncthreads();
    if (tid < OO) {
        {
            float s = fcs_b0[tid];
            for (int j = 0; j < 32; ++j) s += fcs_w0[tid * 32 + j] * fcv[j];
            atts[b * 192 + 0 * OO + tid] = s;
        }
        {
            float s = fcs_b1[tid];
            for (int j = 0; j < 32; ++j) s += fcs_w1[tid * 32 + j] * fcv[j];
            atts[b * 192 + 1 * OO + tid] = s;
        }
        {
            float s = fcs_b2[tid];
            for (int j = 0; j < 32; ++j) s += fcs_w2[tid * 32 + j] * fcv[j];
            atts[b * 192 + 2 * OO + tid] = s;
        }
    }
}

// ---------------- final GEMM: relu(conv_wt^T @ (outbuf .* atts)) ----------
__global__ __launch_bounds__(256)
void final_gemm_kernel(const float* __restrict__ outbuf, const float* __restrict__ atts,
                       const float* __restrict__ conv_wt, const float* __restrict__ conv_b,
                       float* __restrict__ out) {
    __shared__ float As[64][68];
    __shared__ float Bs[64][132];
    int nb0 = blockIdx.x * 128;
    int b = nb0 / HWP, p0 = nb0 % HWP;
    int tid = threadIdx.x;
    int tm = (tid & 15) * 4;
    int tn = (tid >> 4) * 8;
    const float* at = atts + b * 192;

    f32x4 aA0 = 0.f, aA1 = 0.f, aB0 = 0.f, aB1 = 0.f;
    f32x4 aC0 = 0.f, aC1 = 0.f, aD0 = 0.f, aD1 = 0.f;
    for (int kc = 0; kc < 3; ++kc) {
        for (int i4 = tid; i4 < 64 * 16; i4 += 256) {
            int row = i4 >> 4, c4 = (i4 & 15) * 4;
            float4 v = *(const float4*)(conv_wt + (size_t)(kc * 64 + row) * OO + c4);
            As[row][c4] = v.x; As[row][c4 + 1] = v.y; As[row][c4 + 2] = v.z; As[row][c4 + 3] = v.w;
        }
        const float* bp = outbuf + ((size_t)(b * 192 + kc * 64)) * HWP + p0;
        for (int i4 = tid; i4 < 64 * 32; i4 += 256) {
            int row = i4 >> 5, f4 = (i4 & 31) * 4;
            float sc = at[kc * 64 + row];
            float4 v = *(const float4*)(bp + (size_t)row * HWP + f4);
            Bs[row][f4] = v.x * sc; Bs[row][f4 + 1] = v.y * sc;
            Bs[row][f4 + 2] = v.z * sc; Bs[row][f4 + 3] = v.w * sc;
        }
        __syncthreads();
#pragma unroll 4
        for (int kk = 0; kk < 64; ++kk) {
            f32x4 a  = *(const f32x4*)&As[kk][tm];
            f32x4 b0 = *(const f32x4*)&Bs[kk][tn];
            f32x4 b1 = *(const f32x4*)&Bs[kk][tn + 4];
#pragma unroll
            for (int j = 0; j < 4; ++j) {
                aA0[j] += a[0] * b0[j];  aA1[j] += a[0] * b1[j];
                aB0[j] += a[1] * b0[j];  aB1[j] += a[1] * b1[j];
                aC0[j] += a[2] * b0[j];  aC1[j] += a[2] * b1[j];
                aD0[j] += a[3] * b0[j];  aD1[j] += a[3] * b1[j];
            }
        }
        __syncthreads();
    }
    f32x4 accs[8] = {aA0, aA1, aB0, aB1, aC0, aC1, aD0, aD1};
#pragma unroll
    for (int row = 0; row < 4; ++row) {
        int ch = tm + row;
        float bi = conv_b[ch];
        float* ptr = out + ((size_t)(b * OO + ch)) * HWP + p0 + tn;
        f32x4 lo = accs[row * 2], hi = accs[row * 2 + 1];
#pragma unroll
        for (int j = 0; j < 4; ++j) {
            lo[j] += bi; hi[j] += bi;
            lo[j] = lo[j] > 0.f ? lo[j] : 0.f;
            hi[j] = hi[j] > 0.f ? hi[j] : 0.f;
        }
        *(f32x4*)ptr = lo;
        *(f32x4*)(ptr + 4) = hi;
    }
}

extern "C" void kernel_launch(void* const* d_in, const int* in_sizes, int n_in,
                              void* d_out, int out_size, void* d_ws, size_t ws_size,
                              hipStream_t stream) {
    const float* fea    = (const float*)d_in[0];
    const float* inputs = (const float*)d_in[1];
    const float* dw_w[3]  = {(const float*)d_in[2],  (const float*)d_in[8],  (const float*)d_in[14]};
    const float* dw_b[3]  = {(const float*)d_in[3],  (const float*)d_in[9],  (const float*)d_in[15]};
    const float* pw_w[3]  = {(const float*)d_in[4],  (const float*)d_in[10], (const float*)d_in[16]};
    const float* pw_b[3]  = {(const float*)d_in[5],  (const float*)d_in[11], (const float*)d_in[17]};
    const float* dcn_w[3] = {(const float*)d_in[6],  (const float*)d_in[12], (const float*)d_in[18]};
    const float* dcn_b[3] = {(const float*)d_in[7],  (const float*)d_in[13], (const float*)d_in[19]};
    const float* attn_w = (const float*)d_in[20];
    const float* attn_b = (const float*)d_in[21];
    const float* fc_w   = (const float*)d_in[22];
    const float* fc_b   = (const float*)d_in[23];
    const float* fcs_w[3] = {(const float*)d_in[24], (const float*)d_in[26], (const float*)d_in[28]};
    const float* fcs_b[3] = {(const float*)d_in[25], (const float*)d_in[27], (const float*)d_in[29]};
    const float* conv_w = (const float*)d_in[30];
    const float* conv_b = (const float*)d_in[31];
    float* out = (float*)d_out;

    const size_t F_OUTBUF = (size_t)BB * 3 * OO * HWP;   // 28,311,552
    const size_t F_SMALL  = 73728 + 768 + 512 + 4096 + 11264 + 12288 + 12288;
    float* W = (float*)d_ws;
    float* outbuf = W;            W += F_OUTBUF;
    size_t avail = (ws_size / 4 > F_OUTBUF + F_SMALL) ? (ws_size / 4 - F_OUTBUF - F_SMALL) : 0;
    int T = (int)(avail / (4 * (size_t)NTOT));   // om 3T rows + s T rows
    if (T > 64) T = 64;                          // acc_gemm LDS cap
    if (T < 1) T = 1;
    float* om = W;                W += (size_t)3 * T * NTOT;
    float* sbuf = W;              W += (size_t)T * NTOT;
    float* partial = W;           W += 73728;    // BB*PBLK2*64
    float* atts = W;              W += 768;
    float* dcn_wt0 = W;           W += 512;
    float* dcn_wt1 = W;           W += 4096;
    float* dcn_wt2 = W;           W += 11264;
    float* attn_wt = W;           W += 12288;
    float* conv_wt = W;           W += 12288;
    float* dwscr = out;           // d_out as dw-plane scratch; final_gemm rewrites d_out

    transpose_kernel<<<(192 * 64 + 255) / 256, 256, 0, stream>>>(attn_w, attn_wt, 64, 192);
    transpose_kernel<<<(192 * 64 + 255) / 256, 256, 0, stream>>>(conv_w, conv_wt, 64, 192);
    transpose_kernel<<<(7 * 64 + 255) / 256, 256, 0, stream>>>(dcn_w[0], dcn_wt0, 64, 7);
    transpose_kernel<<<(63 * 64 + 255) / 256, 256, 0, stream>>>(dcn_w[1], dcn_wt1, 64, 63);
    transpose_kernel<<<(175 * 64 + 255) / 256, 256, 0, stream>>>(dcn_w[2], dcn_wt2, 64, 175);

    const int dwv_grid = (BB * CF * HH * 48) / 256;   // 9216
    const int pix_grid = BB * PIX_BLOCKS;             // 576
    const int samp_grid = 2 * (NTOT / 256);           // 1152
    const int acc_grid = NTOT / 128;                  // 1152
    const int ntiles = NTOT / 128;                    // 1152

    // ---- k=5 branch ----
    dwv_kernel<5><<<dwv_grid, 256, 0, stream>>>(fea, dw_w[2], dw_b[2], dwscr);
    {
        const int TT = 175;
        for (int t0 = 0; t0 < TT; t0 += T) {
            int t1 = (t0 + T < TT) ? (t0 + T) : TT;
            int Tc = t1 - t0, M = 3 * Tc;
            int mt = (M + 63) / 64;
            pw_gemm_kernel<<<mt * ntiles, 256, 0, stream>>>(pw_w[2], pw_b[2], dwscr, om,
                                                            2 * t0, 2 * Tc, 2 * TT + t0, M);
            sample_kernel<5><<<samp_grid, 256, 0, stream>>>(om, inputs, sbuf, t0, t1);
            int flags = (t0 == 0 ? 1 : 0) | (t1 == TT ? 2 : 0);
            acc_gemm_kernel<<<acc_grid, 256, 0, stream>>>(dcn_wt2, dcn_b[2], sbuf, outbuf,
                                                          2, t0, t1, flags);
        }
    }
    // ---- k=3 branch ----
    dwv_kernel<3><<<dwv_grid, 256, 0, stream>>>(fea, dw_w[1], dw_b[1], dwscr);
    {
        const int TT = 63;
        for (int t0 = 0; t0 < TT; t0 += T) {
            int t1 = (t0 + T < TT) ? (t0 + T) : TT;
            int Tc = t1 - t0, M = 3 * Tc;
            int mt = (M + 63) / 64;
            pw_gemm_kernel<<<mt * ntiles, 256, 0, stream>>>(pw_w[1], pw_b[1], dwscr, om,
                                                            2 * t0, 2 * Tc, 2 * TT + t0, M);
            sample_kernel<3><<<samp_grid, 256, 0, stream>>>(om, inputs, sbuf, t0, t1);
            int flags = (t0 == 0 ? 1 : 0) | (t1 == TT ? 2 : 0);
            acc_gemm_kernel<<<acc_grid, 256, 0, stream>>>(dcn_wt1, dcn_b[1], sbuf, outbuf,
                                                          1, t0, t1, flags);
        }
    }
    // ---- k=1 branch ----
    branch_k1_kernel<<<pix_grid, 256, 0, stream>>>(fea, dw_w[0], dw_b[0], pw_w[0], pw_b[0],
                                                   inputs, dcn_wt0, dcn_b[0], outbuf);

    // ---- attention + final (tiled GEMMs) ----
    attn_gemm_kernel<<<NTOT / 128, 256, 0, stream>>>(outbuf, attn_wt, attn_b, partial);
    attn_finish_kernel<<<BB, 64, 0, stream>>>(partial, fc_w, fc_b,
                                              fcs_w[0], fcs_b[0], fcs_w[1], fcs_b[1],
                                              fcs_w[2], fcs_b[2], atts);
    final_gemm_kernel<<<NTOT / 128, 256, 0, stream>>>(outbuf, atts, conv_wt, conv_b, out);
}

// Round 12
// 732.570 us; speedup vs baseline: 1.0245x; 1.0245x over previous
//
#include <hip/hip_runtime.h>
#include <math.h>

#define HH 192
#define WW 192
#define HWP (192*192)
#define BB 4
#define CF 64
#define NC 7
#define OO 64
#define NTOT (BB*HWP)          // 147456
#define PIX_BLOCKS (HWP/256)   // 144
#define PBLK2 (HWP/128)        // 288

typedef float f32x16 __attribute__((ext_vector_type(16)));
typedef float f32x4  __attribute__((ext_vector_type(4)));

// ---------------- vectorized depthwise conv: 4 outputs/thread -------------
template<int k>
__global__ __launch_bounds__(256)
void dwv_kernel(const float* __restrict__ fea, const float* __restrict__ w,
                const float* __restrict__ bias, float* __restrict__ out) {
    constexpr int pad = k / 2;
    int idx = blockIdx.x * 256 + threadIdx.x;      // over B*CF*HH*48
    int xq = idx % 48;
    int x0 = xq * 4;
    int hpos = (idx / 48) % HH;
    int plane = idx / (48 * HH);                   // uniform per block
    int c = plane % CF;
    const float* f = fea + (size_t)plane * HWP;

    float wk[k * k];
#pragma unroll
    for (int i = 0; i < k * k; ++i) wk[i] = w[c * k * k + i];

    float acc0 = 0.f, acc1 = 0.f, acc2 = 0.f, acc3 = 0.f;
#pragma unroll
    for (int dy = 0; dy < k; ++dy) {
        int y = hpos + dy - pad;
        if (y < 0 || y >= HH) continue;
        const float* row = f + y * WW;
        float4 q0 = (x0 >= 4) ? *(const float4*)(row + x0 - 4) : make_float4(0.f, 0.f, 0.f, 0.f);
        float4 q1 = *(const float4*)(row + x0);
        float4 q2 = (x0 + 4 < WW) ? *(const float4*)(row + x0 + 4) : make_float4(0.f, 0.f, 0.f, 0.f);
        float wnd[8] = {q0.z, q0.w, q1.x, q1.y, q1.z, q1.w, q2.x, q2.y};
#pragma unroll
        for (int dx = 0; dx < k; ++dx) {
            float wt = wk[dy * k + dx];
            acc0 += wnd[0 + dx + 2 - pad] * wt;
            acc1 += wnd[1 + dx + 2 - pad] * wt;
            acc2 += wnd[2 + dx + 2 - pad] * wt;
            acc3 += wnd[3 + dx + 2 - pad] * wt;
        }
    }
    float b = bias[c];
    float4 o = make_float4(acc0 + b, acc1 + b, acc2 + b, acc3 + b);
    *(float4*)(out + (size_t)plane * HWP + hpos * WW + x0) = o;
}

// ---------------- generic small transpose ----------------
__global__ void transpose_kernel(const float* __restrict__ in, float* __restrict__ out,
                                 int rows, int cols) {
    int idx = blockIdx.x * 256 + threadIdx.x;
    if (idx >= rows * cols) return;
    int r = idx / cols, c = idx % cols;
    out[c * rows + r] = in[idx];
}

// ---------------- pw GEMM: om[m][NTOT] = pw_w[src(m)][:] @ dw + pw_b -------
__global__ __launch_bounds__(256)
void pw_gemm_kernel(const float* __restrict__ pw_w, const float* __restrict__ pw_b,
                    const float* __restrict__ dw, float* __restrict__ om,
                    int src0, int n_yx, int src1, int M) {
    __shared__ float As[64][68];
    __shared__ float Bs[64][132];
    const int ntiles = NTOT / 128;
    int ntile = blockIdx.x % ntiles;
    int mtile = blockIdx.x / ntiles;
    int nb0 = ntile * 128;
    int mb0 = mtile * 64;
    int tid = threadIdx.x;

    {
        int m = tid & 63;
        int kq = tid >> 6;
        int gm = mb0 + m;
        int srow = (gm < M) ? ((gm < n_yx) ? (src0 + gm) : (src1 + (gm - n_yx))) : src0;
        const float* ap = pw_w + (size_t)srow * CF;
#pragma unroll
        for (int i = 0; i < 4; ++i) {
            int k0 = (kq * 4 + i) * 4;
            float4 v = *(const float4*)(ap + k0);
            As[k0 + 0][m] = v.x; As[k0 + 1][m] = v.y;
            As[k0 + 2][m] = v.z; As[k0 + 3][m] = v.w;
        }
    }
    {
        int b = nb0 / HWP;
        int p0 = nb0 % HWP;
        const float* bp = dw + (size_t)b * CF * HWP + p0;
#pragma unroll
        for (int i = 0; i < 8; ++i) {
            int idx = tid + i * 256;
            int kk = idx >> 5;
            int f4 = idx & 31;
            float4 v = *(const float4*)(bp + (size_t)kk * HWP + f4 * 4);
            *(float4*)&Bs[kk][f4 * 4] = v;
        }
    }
    __syncthreads();

    int tm = (tid & 15) * 4;
    int tn = (tid >> 4) * 8;
    f32x4 aA0 = 0.f, aA1 = 0.f, aB0 = 0.f, aB1 = 0.f;
    f32x4 aC0 = 0.f, aC1 = 0.f, aD0 = 0.f, aD1 = 0.f;
#pragma unroll 8
    for (int kk = 0; kk < 64; ++kk) {
        f32x4 a  = *(const f32x4*)&As[kk][tm];
        f32x4 b0 = *(const f32x4*)&Bs[kk][tn];
        f32x4 b1 = *(const f32x4*)&Bs[kk][tn + 4];
#pragma unroll
        for (int j = 0; j < 4; ++j) {
            aA0[j] += a[0] * b0[j];  aA1[j] += a[0] * b1[j];
            aB0[j] += a[1] * b0[j];  aB1[j] += a[1] * b1[j];
            aC0[j] += a[2] * b0[j];  aC1[j] += a[2] * b1[j];
            aD0[j] += a[3] * b0[j];  aD1[j] += a[3] * b1[j];
        }
    }
    {
        int gm = mb0 + tm;
        float* dst = om + (size_t)gm * NTOT + nb0 + tn;
        if (gm < M) {
            float bi = pw_b[(gm < n_yx) ? (src0 + gm) : (src1 + gm - n_yx)];
#pragma unroll
            for (int j = 0; j < 4; ++j) { dst[j] = aA0[j] + bi; dst[4 + j] = aA1[j] + bi; }
        }
        gm++; dst += NTOT;
        if (gm < M) {
            float bi = pw_b[(gm < n_yx) ? (src0 + gm) : (src1 + gm - n_yx)];
#pragma unroll
            for (int j = 0; j < 4; ++j) { dst[j] = aB0[j] + bi; dst[4 + j] = aB1[j] + bi; }
        }
        gm++; dst += NTOT;
        if (gm < M) {
            float bi = pw_b[(gm < n_yx) ? (src0 + gm) : (src1 + gm - n_yx)];
#pragma unroll
            for (int j = 0; j < 4; ++j) { dst[j] = aC0[j] + bi; dst[4 + j] = aC1[j] + bi; }
        }
        gm++; dst += NTOT;
        if (gm < M) {
            float bi = pw_b[(gm < n_yx) ? (src0 + gm) : (src1 + gm - n_yx)];
#pragma unroll
            for (int j = 0; j < 4; ++j) { dst[j] = aD0[j] + bi; dst[4 + j] = aD1[j] + bi; }
        }
    }
}

// ---------------- sampling only: s[tap][pixel] ----------------------------
template<int k>
__global__ __launch_bounds__(256)
void sample_kernel(const float* __restrict__ om, const float* __restrict__ inputs,
                   float* __restrict__ sbuf, int t0, int t1) {
    constexpr int K = k * k;
    constexpr int pad = k / 2;
    const int T = t1 - t0;
    int g = blockIdx.x / (NTOT / 256);
    int nb = blockIdx.x % (NTOT / 256);
    int n = nb * 256 + threadIdx.x;
    int b = n / HWP, p = n % HWP;
    int h = p / WW, wq = p % WW;
    const float* inb = inputs + (size_t)b * NC * HWP;
    int half = (T + 1) >> 1;
    int i0 = g * half;
    int i1 = min(T, i0 + half);
#pragma unroll 2
    for (int i = i0; i < i1; ++i) {
        int r = t0 + i;
        float oy = om[(size_t)(2 * i) * NTOT + n];
        float ox = om[(size_t)(2 * i + 1) * NTOT + n];
        float mr = om[(size_t)(2 * T + i) * NTOT + n];
        int c = r / K;
        int kk = r - c * K;
        int ky = kk / k, kx = kk - ky * k;
        const float* inc_ = inb + (size_t)c * HWP;
        float m = 1.f / (1.f + __expf(-mr));
        float py = oy + (float)(ky + h - pad);
        float px = ox + (float)(kx + wq - pad);
        float y0 = floorf(py), x0 = floorf(px);
        float wyf = py - y0, wxf = px - x0;
        int iy0 = (int)y0, ix0 = (int)x0;
        bool y0v = (iy0 >= 0) && (iy0 < HH);
        bool y1v = (iy0 + 1 >= 0) && (iy0 + 1 < HH);
        bool x0v = (ix0 >= 0) && (ix0 < WW);
        bool x1v = (ix0 + 1 >= 0) && (ix0 + 1 < WW);
        int yc0 = min(max(iy0, 0), HH - 1), yc1 = min(max(iy0 + 1, 0), HH - 1);
        int xc0 = min(max(ix0, 0), WW - 1), xc1 = min(max(ix0 + 1, 0), WW - 1);
        float v00 = 0.f, v01 = 0.f, v10 = 0.f, v11 = 0.f;
        if (y0v) {
            if (x0v) v00 = inc_[yc0 * WW + xc0];
            if (x1v) v01 = inc_[yc0 * WW + xc1];
        }
        if (y1v) {
            if (x0v) v10 = inc_[yc1 * WW + xc0];
            if (x1v) v11 = inc_[yc1 * WW + xc1];
        }
        float s = (v00 * (1.f - wyf) * (1.f - wxf) + v01 * (1.f - wyf) * wxf +
                   v10 * wyf * (1.f - wxf) + v11 * wyf * wxf) * m;
        sbuf[(size_t)i * NTOT + n] = s;
    }
}

// ---------------- accumulation GEMM: outbuf[64][N] (+)= wt^T @ s ----------
__global__ __launch_bounds__(256)
void acc_gemm_kernel(const float* __restrict__ wt,     // [T_all][64]
                     const float* __restrict__ bias,
                     const float* __restrict__ sbuf,   // [T][NTOT] chunk-local
                     float* __restrict__ outbuf, int t_slot,
                     int t0, int t1, int flags) {
    __shared__ float As[64][68];
    __shared__ float Bs[64][132];
    const int T = t1 - t0;          // <= 64
    int nb0 = blockIdx.x * 128;
    int tid = threadIdx.x;

    for (int i4 = tid; i4 < T * 16; i4 += 256) {
        int row = i4 >> 4, c4 = (i4 & 15) * 4;
        float4 v = *(const float4*)(wt + (size_t)(t0 + row) * OO + c4);
        As[row][c4] = v.x; As[row][c4 + 1] = v.y; As[row][c4 + 2] = v.z; As[row][c4 + 3] = v.w;
    }
    for (int i4 = tid; i4 < T * 32; i4 += 256) {
        int row = i4 >> 5, f4 = (i4 & 31) * 4;
        float4 v = *(const float4*)(sbuf + (size_t)row * NTOT + nb0 + f4);
        *(float4*)&Bs[row][f4] = v;
    }
    __syncthreads();

    int tm = (tid & 15) * 4;   // channel
    int tn = (tid >> 4) * 8;   // pixel
    f32x4 aA0 = 0.f, aA1 = 0.f, aB0 = 0.f, aB1 = 0.f;
    f32x4 aC0 = 0.f, aC1 = 0.f, aD0 = 0.f, aD1 = 0.f;
#pragma unroll 2
    for (int kk = 0; kk < T; ++kk) {
        f32x4 a  = *(const f32x4*)&As[kk][tm];
        f32x4 b0 = *(const f32x4*)&Bs[kk][tn];
        f32x4 b1 = *(const f32x4*)&Bs[kk][tn + 4];
#pragma unroll
        for (int j = 0; j < 4; ++j) {
            aA0[j] += a[0] * b0[j];  aA1[j] += a[0] * b1[j];
            aB0[j] += a[1] * b0[j];  aB1[j] += a[1] * b1[j];
            aC0[j] += a[2] * b0[j];  aC1[j] += a[2] * b1[j];
            aD0[j] += a[3] * b0[j];  aD1[j] += a[3] * b1[j];
        }
    }

    int b = nb0 / HWP, p0 = nb0 % HWP;
    f32x4 accs[8] = {aA0, aA1, aB0, aB1, aC0, aC1, aD0, aD1};
#pragma unroll
    for (int row = 0; row < 4; ++row) {
        int ch = tm + row;
        float* ptr = outbuf + ((size_t)((b * 3 + t_slot) * OO + ch)) * HWP + p0 + tn;
        f32x4 lo = accs[row * 2], hi = accs[row * 2 + 1];
        if (!(flags & 1)) {
            f32x4 o0 = *(const f32x4*)ptr;
            f32x4 o1 = *(const f32x4*)(ptr + 4);
#pragma unroll
            for (int j = 0; j < 4; ++j) { lo[j] += o0[j]; hi[j] += o1[j]; }
        }
        if (flags & 2) {
            float bi = bias[ch];
#pragma unroll
            for (int j = 0; j < 4; ++j) {
                lo[j] += bi; hi[j] += bi;
                lo[j] = lo[j] > 0.f ? lo[j] : 0.f;
                hi[j] = hi[j] > 0.f ? hi[j] : 0.f;
            }
        }
        *(f32x4*)ptr = lo;
        *(f32x4*)(ptr + 4) = hi;
    }
}

// ---------------- k=1 branch: fused elementwise dw + 7-tap deform ---------
__global__ __launch_bounds__(256)
void branch_k1_kernel(const float* __restrict__ fea,
                      const float* __restrict__ dw_w0, const float* __restrict__ dw_b0,
                      const float* __restrict__ pw_w, const float* __restrict__ pw_b,
                      const float* __restrict__ inputs,
                      const float* __restrict__ dcn_wt, const float* __restrict__ dcn_b,
                      float* __restrict__ outbuf) {
    __shared__ float lw[21 * 64];
    for (int i = threadIdx.x; i < 21 * 16; i += 256)
        ((float4*)lw)[i] = ((const float4*)pw_w)[i];
    __syncthreads();
    int gid = blockIdx.x;
    int b = gid / PIX_BLOCKS;
    int p = (gid % PIX_BLOCKS) * 256 + threadIdx.x;
    int h = p / WW, wq = p % WW;
    const float* inb = inputs + (size_t)b * NC * HWP;

    f32x16 dwv0, dwv1, dwv2, dwv3;
    {
        const float* fp = fea + (size_t)(b * CF) * HWP + p;
#pragma unroll
        for (int j = 0; j < 16; ++j) dwv0[j] = fp[(size_t)j * HWP] * dw_w0[j] + dw_b0[j];
#pragma unroll
        for (int j = 0; j < 16; ++j) dwv1[j] = fp[(size_t)(16 + j) * HWP] * dw_w0[16 + j] + dw_b0[16 + j];
#pragma unroll
        for (int j = 0; j < 16; ++j) dwv2[j] = fp[(size_t)(32 + j) * HWP] * dw_w0[32 + j] + dw_b0[32 + j];
#pragma unroll
        for (int j = 0; j < 16; ++j) dwv3[j] = fp[(size_t)(48 + j) * HWP] * dw_w0[48 + j] + dw_b0[48 + j];
    }
    f32x16 acc0, acc1, acc2, acc3;
#pragma unroll
    for (int j = 0; j < 16; ++j) { acc0[j] = 0.f; acc1[j] = 0.f; acc2[j] = 0.f; acc3[j] = 0.f; }

    for (int r = 0; r < NC; ++r) {
        const float* wy = lw + (2 * r) * 64;
        const float* wx = wy + 64;
        const float* wm = lw + (14 + r) * 64;
        const float* inc_ = inb + (size_t)r * HWP;
        float oy = pw_b[2 * r], ox = pw_b[2 * r + 1], om = pw_b[14 + r];
#pragma unroll
        for (int j = 0; j < 16; ++j) { oy += wy[j] * dwv0[j];      ox += wx[j] * dwv0[j];      om += wm[j] * dwv0[j]; }
#pragma unroll
        for (int j = 0; j < 16; ++j) { oy += wy[16 + j] * dwv1[j]; ox += wx[16 + j] * dwv1[j]; om += wm[16 + j] * dwv1[j]; }
#pragma unroll
        for (int j = 0; j < 16; ++j) { oy += wy[32 + j] * dwv2[j]; ox += wx[32 + j] * dwv2[j]; om += wm[32 + j] * dwv2[j]; }
#pragma unroll
        for (int j = 0; j < 16; ++j) { oy += wy[48 + j] * dwv3[j]; ox += wx[48 + j] * dwv3[j]; om += wm[48 + j] * dwv3[j]; }
        float m = 1.f / (1.f + __expf(-om));
        float py = oy + (float)h;
        float px = ox + (float)wq;
        float y0 = floorf(py), x0 = floorf(px);
        float wyf = py - y0, wxf = px - x0;
        int iy0 = (int)y0, ix0 = (int)x0;
        bool y0v = (iy0 >= 0) && (iy0 < HH);
        bool y1v = (iy0 + 1 >= 0) && (iy0 + 1 < HH);
        bool x0v = (ix0 >= 0) && (ix0 < WW);
        bool x1v = (ix0 + 1 >= 0) && (ix0 + 1 < WW);
        int yc0 = min(max(iy0, 0), HH - 1), yc1 = min(max(iy0 + 1, 0), HH - 1);
        int xc0 = min(max(ix0, 0), WW - 1), xc1 = min(max(ix0 + 1, 0), WW - 1);
        float v00 = 0.f, v01 = 0.f, v10 = 0.f, v11 = 0.f;
        if (y0v) {
            if (x0v) v00 = inc_[yc0 * WW + xc0];
            if (x1v) v01 = inc_[yc0 * WW + xc1];
        }
        if (y1v) {
            if (x0v) v10 = inc_[yc1 * WW + xc0];
            if (x1v) v11 = inc_[yc1 * WW + xc1];
        }
        float s = (v00 * (1.f - wyf) * (1.f - wxf) + v01 * (1.f - wyf) * wxf +
                   v10 * wyf * (1.f - wxf) + v11 * wyf * wxf) * m;
        const float* dt = dcn_wt + (size_t)r * OO;
#pragma unroll
        for (int j = 0; j < 16; ++j) acc0[j] += s * dt[j];
#pragma unroll
        for (int j = 0; j < 16; ++j) acc1[j] += s * dt[16 + j];
#pragma unroll
        for (int j = 0; j < 16; ++j) acc2[j] += s * dt[32 + j];
#pragma unroll
        for (int j = 0; j < 16; ++j) acc3[j] += s * dt[48 + j];
    }
    float* op = outbuf + (size_t)(b * 3 * OO) * HWP + p;
#pragma unroll
    for (int j = 0; j < 16; ++j) { float v = acc0[j] + dcn_b[j];      op[(size_t)j * HWP] = v > 0.f ? v : 0.f; }
#pragma unroll
    for (int j = 0; j < 16; ++j) { float v = acc1[j] + dcn_b[16 + j]; op[(size_t)(16 + j) * HWP] = v > 0.f ? v : 0.f; }
#pragma unroll
    for (int j = 0; j < 16; ++j) { float v = acc2[j] + dcn_b[32 + j]; op[(size_t)(32 + j) * HWP] = v > 0.f ? v : 0.f; }
#pragma unroll
    for (int j = 0; j < 16; ++j) { float v = acc3[j] + dcn_b[48 + j]; op[(size_t)(48 + j) * HWP] = v > 0.f ? v : 0.f; }
}

// ---------------- attention GEMM, KC=32 LDS chunks ------------------------
// Round-11 lesson: 54.5KB LDS -> 2 blocks/CU -> 16% occupancy ate the reuse
// win. KC=32 chunks: ~30KB -> 5 blocks/CU.
__global__ __launch_bounds__(256)
void attn_gemm_kernel(const float* __restrict__ outbuf, const float* __restrict__ attn_wt,
                      const float* __restrict__ attn_b, float* __restrict__ partial) {
    __shared__ float As[32][68];
    __shared__ float Bs[32][132];
    __shared__ float red[16][68];
    int nb0 = blockIdx.x * 128;
    int b = nb0 / HWP, p0 = nb0 % HWP;
    int tid = threadIdx.x;
    int tm = (tid & 15) * 4;
    int tn = (tid >> 4) * 8;

    f32x4 aA0 = 0.f, aA1 = 0.f, aB0 = 0.f, aB1 = 0.f;
    f32x4 aC0 = 0.f, aC1 = 0.f, aD0 = 0.f, aD1 = 0.f;
    for (int kc = 0; kc < 6; ++kc) {
        for (int i4 = tid; i4 < 32 * 16; i4 += 256) {
            int row = i4 >> 4, c4 = (i4 & 15) * 4;
            float4 v = *(const float4*)(attn_wt + (size_t)(kc * 32 + row) * OO + c4);
            As[row][c4] = v.x; As[row][c4 + 1] = v.y; As[row][c4 + 2] = v.z; As[row][c4 + 3] = v.w;
        }
        const float* bp = outbuf + ((size_t)(b * 192 + kc * 32)) * HWP + p0;
        for (int i4 = tid; i4 < 32 * 32; i4 += 256) {
            int row = i4 >> 5, f4 = (i4 & 31) * 4;
            float4 v = *(const float4*)(bp + (size_t)row * HWP + f4);
            *(float4*)&Bs[row][f4] = v;
        }
        __syncthreads();
#pragma unroll 4
        for (int kk = 0; kk < 32; ++kk) {
            f32x4 a  = *(const f32x4*)&As[kk][tm];
            f32x4 b0 = *(const f32x4*)&Bs[kk][tn];
            f32x4 b1 = *(const f32x4*)&Bs[kk][tn + 4];
#pragma unroll
            for (int j = 0; j < 4; ++j) {
                aA0[j] += a[0] * b0[j];  aA1[j] += a[0] * b1[j];
                aB0[j] += a[1] * b0[j];  aB1[j] += a[1] * b1[j];
                aC0[j] += a[2] * b0[j];  aC1[j] += a[2] * b1[j];
                aD0[j] += a[3] * b0[j];  aD1[j] += a[3] * b1[j];
            }
        }
        __syncthreads();
    }
    float bsum[4];
    {
        f32x4 accs[8] = {aA0, aA1, aB0, aB1, aC0, aC1, aD0, aD1};
#pragma unroll
        for (int row = 0; row < 4; ++row) {
            float bi = attn_b[tm + row];
            float s = 0.f;
#pragma unroll
            for (int j = 0; j < 4; ++j) {
                float v0 = accs[row * 2][j] + bi;
                float v1 = accs[row * 2 + 1][j] + bi;
                s += (v0 > 0.f ? v0 : 0.f) + (v1 > 0.f ? v1 : 0.f);
            }
            bsum[row] = s;
        }
    }
    int pg = tid >> 4;
#pragma unroll
    for (int row = 0; row < 4; ++row) red[pg][tm + row] = bsum[row];
    __syncthreads();
    if (tid < 64) {
        float s = 0.f;
#pragma unroll
        for (int g = 0; g < 16; ++g) s += red[g][tid];
        int lb = p0 / 128;
        partial[((size_t)(b * PBLK2 + lb)) * OO + tid] = s;
    }
}

// ---------------- attention finish ----------------
__global__ void attn_finish_kernel(const float* __restrict__ partial,
                                   const float* __restrict__ fc_w, const float* __restrict__ fc_b,
                                   const float* __restrict__ fcs_w0, const float* __restrict__ fcs_b0,
                                   const float* __restrict__ fcs_w1, const float* __restrict__ fcs_b1,
                                   const float* __restrict__ fcs_w2, const float* __restrict__ fcs_b2,
                                   float* __restrict__ atts) {
    int b = blockIdx.x;
    __shared__ float attm[OO];
    __shared__ float fcv[32];
    int tid = threadIdx.x;
    if (tid < OO) {
        float s = 0.f;
        for (int blk = 0; blk < PBLK2; ++blk)
            s += partial[((size_t)(b * PBLK2 + blk)) * OO + tid];
        attm[tid] = s / (float)HWP;
    }
    __syncthreads();
    if (tid < 32) {
        float s = fc_b[tid];
        for (int o = 0; o < OO; ++o) s += fc_w[tid * OO + o] * attm[o];
        fcv[tid] = s > 0.f ? s : 0.f;
    }
    __syncthreads();
    if (tid < OO) {
        {
            float s = fcs_b0[tid];
            for (int j = 0; j < 32; ++j) s += fcs_w0[tid * 32 + j] * fcv[j];
            atts[b * 192 + 0 * OO + tid] = s;
        }
        {
            float s = fcs_b1[tid];
            for (int j = 0; j < 32; ++j) s += fcs_w1[tid * 32 + j] * fcv[j];
            atts[b * 192 + 1 * OO + tid] = s;
        }
        {
            float s = fcs_b2[tid];
            for (int j = 0; j < 32; ++j) s += fcs_w2[tid * 32 + j] * fcv[j];
            atts[b * 192 + 2 * OO + tid] = s;
        }
    }
}

// ---------------- final GEMM, KC=32 LDS chunks ----------------------------
__global__ __launch_bounds__(256)
void final_gemm_kernel(const float* __restrict__ outbuf, const float* __restrict__ atts,
                       const float* __restrict__ conv_wt, const float* __restrict__ conv_b,
                       float* __restrict__ out) {
    __shared__ float As[32][68];
    __shared__ float Bs[32][132];
    int nb0 = blockIdx.x * 128;
    int b = nb0 / HWP, p0 = nb0 % HWP;
    int tid = threadIdx.x;
    int tm = (tid & 15) * 4;
    int tn = (tid >> 4) * 8;
    const float* at = atts + b * 192;

    f32x4 aA0 = 0.f, aA1 = 0.f, aB0 = 0.f, aB1 = 0.f;
    f32x4 aC0 = 0.f, aC1 = 0.f, aD0 = 0.f, aD1 = 0.f;
    for (int kc = 0; kc < 6; ++kc) {
        for (int i4 = tid; i4 < 32 * 16; i4 += 256) {
            int row = i4 >> 4, c4 = (i4 & 15) * 4;
            float4 v = *(const float4*)(conv_wt + (size_t)(kc * 32 + row) * OO + c4);
            As[row][c4] = v.x; As[row][c4 + 1] = v.y; As[row][c4 + 2] = v.z; As[row][c4 + 3] = v.w;
        }
        const float* bp = outbuf + ((size_t)(b * 192 + kc * 32)) * HWP + p0;
        for (int i4 = tid; i4 < 32 * 32; i4 += 256) {
            int row = i4 >> 5, f4 = (i4 & 31) * 4;
            float sc = at[kc * 32 + row];
            float4 v = *(const float4*)(bp + (size_t)row * HWP + f4);
            Bs[row][f4] = v.x * sc; Bs[row][f4 + 1] = v.y * sc;
            Bs[row][f4 + 2] = v.z * sc; Bs[row][f4 + 3] = v.w * sc;
        }
        __syncthreads();
#pragma unroll 4
        for (int kk = 0; kk < 32; ++kk) {
            f32x4 a  = *(const f32x4*)&As[kk][tm];
            f32x4 b0 = *(const f32x4*)&Bs[kk][tn];
            f32x4 b1 = *(const f32x4*)&Bs[kk][tn + 4];
#pragma unroll
            for (int j = 0; j < 4; ++j) {
                aA0[j] += a[0] * b0[j];  aA1[j] += a[0] * b1[j];
                aB0[j] += a[1] * b0[j];  aB1[j] += a[1] * b1[j];
                aC0[j] += a[2] * b0[j];  aC1[j] += a[2] * b1[j];
                aD0[j] += a[3] * b0[j];  aD1[j] += a[3] * b1[j];
            }
        }
        __syncthreads();
    }
    f32x4 accs[8] = {aA0, aA1, aB0, aB1, aC0, aC1, aD0, aD1};
#pragma unroll
    for (int row = 0; row < 4; ++row) {
        int ch = tm + row;
        float bi = conv_b[ch];
        float* ptr = out + ((size_t)(b * OO + ch)) * HWP + p0 + tn;
        f32x4 lo = accs[row * 2], hi = accs[row * 2 + 1];
#pragma unroll
        for (int j = 0; j < 4; ++j) {
            lo[j] += bi; hi[j] += bi;
            lo[j] = lo[j] > 0.f ? lo[j] : 0.f;
            hi[j] = hi[j] > 0.f ? hi[j] : 0.f;
        }
        *(f32x4*)ptr = lo;
        *(f32x4*)(ptr + 4) = hi;
    }
}

extern "C" void kernel_launch(void* const* d_in, const int* in_sizes, int n_in,
                              void* d_out, int out_size, void* d_ws, size_t ws_size,
                              hipStream_t stream) {
    const float* fea    = (const float*)d_in[0];
    const float* inputs = (const float*)d_in[1];
    const float* dw_w[3]  = {(const float*)d_in[2],  (const float*)d_in[8],  (const float*)d_in[14]};
    const float* dw_b[3]  = {(const float*)d_in[3],  (const float*)d_in[9],  (const float*)d_in[15]};
    const float* pw_w[3]  = {(const float*)d_in[4],  (const float*)d_in[10], (const float*)d_in[16]};
    const float* pw_b[3]  = {(const float*)d_in[5],  (const float*)d_in[11], (const float*)d_in[17]};
    const float* dcn_w[3] = {(const float*)d_in[6],  (const float*)d_in[12], (const float*)d_in[18]};
    const float* dcn_b[3] = {(const float*)d_in[7],  (const float*)d_in[13], (const float*)d_in[19]};
    const float* attn_w = (const float*)d_in[20];
    const float* attn_b = (const float*)d_in[21];
    const float* fc_w   = (const float*)d_in[22];
    const float* fc_b   = (const float*)d_in[23];
    const float* fcs_w[3] = {(const float*)d_in[24], (const float*)d_in[26], (const float*)d_in[28]};
    const float* fcs_b[3] = {(const float*)d_in[25], (const float*)d_in[27], (const float*)d_in[29]};
    const float* conv_w = (const float*)d_in[30];
    const float* conv_b = (const float*)d_in[31];
    float* out = (float*)d_out;

    const size_t F_OUTBUF = (size_t)BB * 3 * OO * HWP;   // 28,311,552
    const size_t F_SMALL  = 73728 + 768 + 512 + 4096 + 11264 + 12288 + 12288;
    float* W = (float*)d_ws;
    float* outbuf = W;            W += F_OUTBUF;
    size_t avail = (ws_size / 4 > F_OUTBUF + F_SMALL) ? (ws_size / 4 - F_OUTBUF - F_SMALL) : 0;
    int T = (int)(avail / (4 * (size_t)NTOT));   // om 3T rows + s T rows
    if (T > 64) T = 64;                          // acc_gemm LDS cap
    if (T < 1) T = 1;
    float* om = W;                W += (size_t)3 * T * NTOT;
    float* sbuf = W;              W += (size_t)T * NTOT;
    float* partial = W;           W += 73728;    // BB*PBLK2*64
    float* atts = W;              W += 768;
    float* dcn_wt0 = W;           W += 512;
    float* dcn_wt1 = W;           W += 4096;
    float* dcn_wt2 = W;           W += 11264;
    float* attn_wt = W;           W += 12288;
    float* conv_wt = W;           W += 12288;
    float* dwscr = out;           // d_out as dw-plane scratch; final_gemm rewrites d_out

    transpose_kernel<<<(192 * 64 + 255) / 256, 256, 0, stream>>>(attn_w, attn_wt, 64, 192);
    transpose_kernel<<<(192 * 64 + 255) / 256, 256, 0, stream>>>(conv_w, conv_wt, 64, 192);
    transpose_kernel<<<(7 * 64 + 255) / 256, 256, 0, stream>>>(dcn_w[0], dcn_wt0, 64, 7);
    transpose_kernel<<<(63 * 64 + 255) / 256, 256, 0, stream>>>(dcn_w[1], dcn_wt1, 64, 63);
    transpose_kernel<<<(175 * 64 + 255) / 256, 256, 0, stream>>>(dcn_w[2], dcn_wt2, 64, 175);

    const int dwv_grid = (BB * CF * HH * 48) / 256;   // 9216
    const int pix_grid = BB * PIX_BLOCKS;             // 576
    const int samp_grid = 2 * (NTOT / 256);           // 1152
    const int acc_grid = NTOT / 128;                  // 1152
    const int ntiles = NTOT / 128;                    // 1152

    // ---- k=5 branch ----
    dwv_kernel<5><<<dwv_grid, 256, 0, stream>>>(fea, dw_w[2], dw_b[2], dwscr);
    {
        const int TT = 175;
        for (int t0 = 0; t0 < TT; t0 += T) {
            int t1 = (t0 + T < TT) ? (t0 + T) : TT;
            int Tc = t1 - t0, M = 3 * Tc;
            int mt = (M + 63) / 64;
            pw_gemm_kernel<<<mt * ntiles, 256, 0, stream>>>(pw_w[2], pw_b[2], dwscr, om,
                                                            2 * t0, 2 * Tc, 2 * TT + t0, M);
            sample_kernel<5><<<samp_grid, 256, 0, stream>>>(om, inputs, sbuf, t0, t1);
            int flags = (t0 == 0 ? 1 : 0) | (t1 == TT ? 2 : 0);
            acc_gemm_kernel<<<acc_grid, 256, 0, stream>>>(dcn_wt2, dcn_b[2], sbuf, outbuf,
                                                          2, t0, t1, flags);
        }
    }
    // ---- k=3 branch ----
    dwv_kernel<3><<<dwv_grid, 256, 0, stream>>>(fea, dw_w[1], dw_b[1], dwscr);
    {
        const int TT = 63;
        for (int t0 = 0; t0 < TT; t0 += T) {
            int t1 = (t0 + T < TT) ? (t0 + T) : TT;
            int Tc = t1 - t0, M = 3 * Tc;
            int mt = (M + 63) / 64;
            pw_gemm_kernel<<<mt * ntiles, 256, 0, stream>>>(pw_w[1], pw_b[1], dwscr, om,
                                                            2 * t0, 2 * Tc, 2 * TT + t0, M);
            sample_kernel<3><<<samp_grid, 256, 0, stream>>>(om, inputs, sbuf, t0, t1);
            int flags = (t0 == 0 ? 1 : 0) | (t1 == TT ? 2 : 0);
            acc_gemm_kernel<<<acc_grid, 256, 0, stream>>>(dcn_wt1, dcn_b[1], sbuf, outbuf,
                                                          1, t0, t1, flags);
        }
    }
    // ---- k=1 branch ----
    branch_k1_kernel<<<pix_grid, 256, 0, stream>>>(fea, dw_w[0], dw_b[0], pw_w[0], pw_b[0],
                                                   inputs, dcn_wt0, dcn_b[0], outbuf);

    // ---- attention + final (tiled GEMMs, KC=32) ----
    attn_gemm_kernel<<<NTOT / 128, 256, 0, stream>>>(outbuf, attn_wt, attn_b, partial);
    attn_finish_kernel<<<BB, 64, 0, stream>>>(partial, fc_w, fc_b,
                                              fcs_w[0], fcs_b[0], fcs_w[1], fcs_b[1],
                                              fcs_w[2], fcs_b[2], atts);
    final_gemm_kernel<<<NTOT / 128, 256, 0, stream>>>(outbuf, atts, conv_wt, conv_b, out);
}

// Round 13
// 730.545 us; speedup vs baseline: 1.0273x; 1.0028x over previous
//
#include <hip/hip_runtime.h>
#include <math.h>

#define HH 192
#define WW 192
#define HWP (192*192)
#define BB 4
#define CF 64
#define NC 7
#define OO 64
#define NTOT (BB*HWP)          // 147456
#define PIX_BLOCKS (HWP/256)   // 144
#define PBLK2 (HWP/128)        // 288

typedef float f32x16 __attribute__((ext_vector_type(16)));
typedef float f32x4  __attribute__((ext_vector_type(4)));

// ---------------- vectorized depthwise conv: 4 outputs/thread -------------
template<int k>
__global__ __launch_bounds__(256)
void dwv_kernel(const float* __restrict__ fea, const float* __restrict__ w,
                const float* __restrict__ bias, float* __restrict__ out) {
    constexpr int pad = k / 2;
    int idx = blockIdx.x * 256 + threadIdx.x;      // over B*CF*HH*48
    int xq = idx % 48;
    int x0 = xq * 4;
    int hpos = (idx / 48) % HH;
    int plane = idx / (48 * HH);                   // uniform per block
    int c = plane % CF;
    const float* f = fea + (size_t)plane * HWP;

    float wk[k * k];
#pragma unroll
    for (int i = 0; i < k * k; ++i) wk[i] = w[c * k * k + i];

    float acc0 = 0.f, acc1 = 0.f, acc2 = 0.f, acc3 = 0.f;
#pragma unroll
    for (int dy = 0; dy < k; ++dy) {
        int y = hpos + dy - pad;
        if (y < 0 || y >= HH) continue;
        const float* row = f + y * WW;
        float4 q0 = (x0 >= 4) ? *(const float4*)(row + x0 - 4) : make_float4(0.f, 0.f, 0.f, 0.f);
        float4 q1 = *(const float4*)(row + x0);
        float4 q2 = (x0 + 4 < WW) ? *(const float4*)(row + x0 + 4) : make_float4(0.f, 0.f, 0.f, 0.f);
        float wnd[8] = {q0.z, q0.w, q1.x, q1.y, q1.z, q1.w, q2.x, q2.y};
#pragma unroll
        for (int dx = 0; dx < k; ++dx) {
            float wt = wk[dy * k + dx];
            acc0 += wnd[0 + dx + 2 - pad] * wt;
            acc1 += wnd[1 + dx + 2 - pad] * wt;
            acc2 += wnd[2 + dx + 2 - pad] * wt;
            acc3 += wnd[3 + dx + 2 - pad] * wt;
        }
    }
    float b = bias[c];
    float4 o = make_float4(acc0 + b, acc1 + b, acc2 + b, acc3 + b);
    *(float4*)(out + (size_t)plane * HWP + hpos * WW + x0) = o;
}

// ---------------- generic small transpose ----------------
__global__ void transpose_kernel(const float* __restrict__ in, float* __restrict__ out,
                                 int rows, int cols) {
    int idx = blockIdx.x * 256 + threadIdx.x;
    if (idx >= rows * cols) return;
    int r = idx / cols, c = idx % cols;
    out[c * rows + r] = in[idx];
}

// ---------------- k1 weight fold: pw_w' = pw_w*diag(w0), b' = pw_b+pw_w@b0
__global__ void k1_fold_kernel(const float* __restrict__ pw_w, const float* __restrict__ pw_b,
                               const float* __restrict__ dw_w0, const float* __restrict__ dw_b0,
                               float* __restrict__ pw_wf, float* __restrict__ pw_bf) {
    int i = blockIdx.x * 256 + threadIdx.x;
    if (i < 21 * 64) pw_wf[i] = pw_w[i] * dw_w0[i & 63];
    if (i < 21) {
        float s = pw_b[i];
        for (int c = 0; c < 64; ++c) s += pw_w[i * 64 + c] * dw_b0[c];
        pw_bf[i] = s;
    }
}

// ---------------- pw GEMM: om[m][NTOT] = pw_w[src(m)][:] @ dw + pw_b -------
__global__ __launch_bounds__(256)
void pw_gemm_kernel(const float* __restrict__ pw_w, const float* __restrict__ pw_b,
                    const float* __restrict__ dw, float* __restrict__ om,
                    int src0, int n_yx, int src1, int M) {
    __shared__ float As[64][68];
    __shared__ float Bs[64][132];
    const int ntiles = NTOT / 128;
    int ntile = blockIdx.x % ntiles;
    int mtile = blockIdx.x / ntiles;
    int nb0 = ntile * 128;
    int mb0 = mtile * 64;
    int tid = threadIdx.x;

    {
        int m = tid & 63;
        int kq = tid >> 6;
        int gm = mb0 + m;
        int srow = (gm < M) ? ((gm < n_yx) ? (src0 + gm) : (src1 + (gm - n_yx))) : src0;
        const float* ap = pw_w + (size_t)srow * CF;
#pragma unroll
        for (int i = 0; i < 4; ++i) {
            int k0 = (kq * 4 + i) * 4;
            float4 v = *(const float4*)(ap + k0);
            As[k0 + 0][m] = v.x; As[k0 + 1][m] = v.y;
            As[k0 + 2][m] = v.z; As[k0 + 3][m] = v.w;
        }
    }
    {
        int b = nb0 / HWP;
        int p0 = nb0 % HWP;
        const float* bp = dw + (size_t)b * CF * HWP + p0;
#pragma unroll
        for (int i = 0; i < 8; ++i) {
            int idx = tid + i * 256;
            int kk = idx >> 5;
            int f4 = idx & 31;
            float4 v = *(const float4*)(bp + (size_t)kk * HWP + f4 * 4);
            *(float4*)&Bs[kk][f4 * 4] = v;
        }
    }
    __syncthreads();

    int tm = (tid & 15) * 4;
    int tn = (tid >> 4) * 8;
    f32x4 aA0 = 0.f, aA1 = 0.f, aB0 = 0.f, aB1 = 0.f;
    f32x4 aC0 = 0.f, aC1 = 0.f, aD0 = 0.f, aD1 = 0.f;
#pragma unroll 8
    for (int kk = 0; kk < 64; ++kk) {
        f32x4 a  = *(const f32x4*)&As[kk][tm];
        f32x4 b0 = *(const f32x4*)&Bs[kk][tn];
        f32x4 b1 = *(const f32x4*)&Bs[kk][tn + 4];
#pragma unroll
        for (int j = 0; j < 4; ++j) {
            aA0[j] += a[0] * b0[j];  aA1[j] += a[0] * b1[j];
            aB0[j] += a[1] * b0[j];  aB1[j] += a[1] * b1[j];
            aC0[j] += a[2] * b0[j];  aC1[j] += a[2] * b1[j];
            aD0[j] += a[3] * b0[j];  aD1[j] += a[3] * b1[j];
        }
    }
    {
        int gm = mb0 + tm;
        float* dst = om + (size_t)gm * NTOT + nb0 + tn;
        if (gm < M) {
            float bi = pw_b[(gm < n_yx) ? (src0 + gm) : (src1 + gm - n_yx)];
#pragma unroll
            for (int j = 0; j < 4; ++j) { dst[j] = aA0[j] + bi; dst[4 + j] = aA1[j] + bi; }
        }
        gm++; dst += NTOT;
        if (gm < M) {
            float bi = pw_b[(gm < n_yx) ? (src0 + gm) : (src1 + gm - n_yx)];
#pragma unroll
            for (int j = 0; j < 4; ++j) { dst[j] = aB0[j] + bi; dst[4 + j] = aB1[j] + bi; }
        }
        gm++; dst += NTOT;
        if (gm < M) {
            float bi = pw_b[(gm < n_yx) ? (src0 + gm) : (src1 + gm - n_yx)];
#pragma unroll
            for (int j = 0; j < 4; ++j) { dst[j] = aC0[j] + bi; dst[4 + j] = aC1[j] + bi; }
        }
        gm++; dst += NTOT;
        if (gm < M) {
            float bi = pw_b[(gm < n_yx) ? (src0 + gm) : (src1 + gm - n_yx)];
#pragma unroll
            for (int j = 0; j < 4; ++j) { dst[j] = aD0[j] + bi; dst[4 + j] = aD1[j] + bi; }
        }
    }
}

// ---------------- sampling only: s[tap][pixel] ----------------------------
template<int k>
__global__ __launch_bounds__(256)
void sample_kernel(const float* __restrict__ om, const float* __restrict__ inputs,
                   float* __restrict__ sbuf, int t0, int t1) {
    constexpr int K = k * k;
    constexpr int pad = k / 2;
    const int T = t1 - t0;
    int g = blockIdx.x / (NTOT / 256);
    int nb = blockIdx.x % (NTOT / 256);
    int n = nb * 256 + threadIdx.x;
    int b = n / HWP, p = n % HWP;
    int h = p / WW, wq = p % WW;
    const float* inb = inputs + (size_t)b * NC * HWP;
    int half = (T + 1) >> 1;
    int i0 = g * half;
    int i1 = min(T, i0 + half);
#pragma unroll 2
    for (int i = i0; i < i1; ++i) {
        int r = t0 + i;
        float oy = om[(size_t)(2 * i) * NTOT + n];
        float ox = om[(size_t)(2 * i + 1) * NTOT + n];
        float mr = om[(size_t)(2 * T + i) * NTOT + n];
        int c = r / K;
        int kk = r - c * K;
        int ky = kk / k, kx = kk - ky * k;
        const float* inc_ = inb + (size_t)c * HWP;
        float m = 1.f / (1.f + __expf(-mr));
        float py = oy + (float)(ky + h - pad);
        float px = ox + (float)(kx + wq - pad);
        float y0 = floorf(py), x0 = floorf(px);
        float wyf = py - y0, wxf = px - x0;
        int iy0 = (int)y0, ix0 = (int)x0;
        bool y0v = (iy0 >= 0) && (iy0 < HH);
        bool y1v = (iy0 + 1 >= 0) && (iy0 + 1 < HH);
        bool x0v = (ix0 >= 0) && (ix0 < WW);
        bool x1v = (ix0 + 1 >= 0) && (ix0 + 1 < WW);
        int yc0 = min(max(iy0, 0), HH - 1), yc1 = min(max(iy0 + 1, 0), HH - 1);
        int xc0 = min(max(ix0, 0), WW - 1), xc1 = min(max(ix0 + 1, 0), WW - 1);
        float v00 = 0.f, v01 = 0.f, v10 = 0.f, v11 = 0.f;
        if (y0v) {
            if (x0v) v00 = inc_[yc0 * WW + xc0];
            if (x1v) v01 = inc_[yc0 * WW + xc1];
        }
        if (y1v) {
            if (x0v) v10 = inc_[yc1 * WW + xc0];
            if (x1v) v11 = inc_[yc1 * WW + xc1];
        }
        float s = (v00 * (1.f - wyf) * (1.f - wxf) + v01 * (1.f - wyf) * wxf +
                   v10 * wyf * (1.f - wxf) + v11 * wyf * wxf) * m;
        sbuf[(size_t)i * NTOT + n] = s;
    }
}

// ---------------- accumulation GEMM: outbuf[64][N] (+)= wt^T @ s ----------
__global__ __launch_bounds__(256)
void acc_gemm_kernel(const float* __restrict__ wt,     // [T_all][64]
                     const float* __restrict__ bias,
                     const float* __restrict__ sbuf,   // [T][NTOT] chunk-local
                     float* __restrict__ outbuf, int t_slot,
                     int t0, int t1, int flags) {
    __shared__ float As[64][68];
    __shared__ float Bs[64][132];
    const int T = t1 - t0;          // <= 64
    int nb0 = blockIdx.x * 128;
    int tid = threadIdx.x;

    for (int i4 = tid; i4 < T * 16; i4 += 256) {
        int row = i4 >> 4, c4 = (i4 & 15) * 4;
        float4 v = *(const float4*)(wt + (size_t)(t0 + row) * OO + c4);
        As[row][c4] = v.x; As[row][c4 + 1] = v.y; As[row][c4 + 2] = v.z; As[row][c4 + 3] = v.w;
    }
    for (int i4 = tid; i4 < T * 32; i4 += 256) {
        int row = i4 >> 5, f4 = (i4 & 31) * 4;
        float4 v = *(const float4*)(sbuf + (size_t)row * NTOT + nb0 + f4);
        *(float4*)&Bs[row][f4] = v;
    }
    __syncthreads();

    int tm = (tid & 15) * 4;   // channel
    int tn = (tid >> 4) * 8;   // pixel
    f32x4 aA0 = 0.f, aA1 = 0.f, aB0 = 0.f, aB1 = 0.f;
    f32x4 aC0 = 0.f, aC1 = 0.f, aD0 = 0.f, aD1 = 0.f;
#pragma unroll 2
    for (int kk = 0; kk < T; ++kk) {
        f32x4 a  = *(const f32x4*)&As[kk][tm];
        f32x4 b0 = *(const f32x4*)&Bs[kk][tn];
        f32x4 b1 = *(const f32x4*)&Bs[kk][tn + 4];
#pragma unroll
        for (int j = 0; j < 4; ++j) {
            aA0[j] += a[0] * b0[j];  aA1[j] += a[0] * b1[j];
            aB0[j] += a[1] * b0[j];  aB1[j] += a[1] * b1[j];
            aC0[j] += a[2] * b0[j];  aC1[j] += a[2] * b1[j];
            aD0[j] += a[3] * b0[j];  aD1[j] += a[3] * b1[j];
        }
    }

    int b = nb0 / HWP, p0 = nb0 % HWP;
    f32x4 accs[8] = {aA0, aA1, aB0, aB1, aC0, aC1, aD0, aD1};
#pragma unroll
    for (int row = 0; row < 4; ++row) {
        int ch = tm + row;
        float* ptr = outbuf + ((size_t)((b * 3 + t_slot) * OO + ch)) * HWP + p0 + tn;
        f32x4 lo = accs[row * 2], hi = accs[row * 2 + 1];
        if (!(flags & 1)) {
            f32x4 o0 = *(const f32x4*)ptr;
            f32x4 o1 = *(const f32x4*)(ptr + 4);
#pragma unroll
            for (int j = 0; j < 4; ++j) { lo[j] += o0[j]; hi[j] += o1[j]; }
        }
        if (flags & 2) {
            float bi = bias[ch];
#pragma unroll
            for (int j = 0; j < 4; ++j) {
                lo[j] += bi; hi[j] += bi;
                lo[j] = lo[j] > 0.f ? lo[j] : 0.f;
                hi[j] = hi[j] > 0.f ? hi[j] : 0.f;
            }
        }
        *(f32x4*)ptr = lo;
        *(f32x4*)(ptr + 4) = hi;
    }
}

// ---------------- k=1 branch fallback (used only if ws too small) ---------
__global__ __launch_bounds__(256)
void branch_k1_kernel(const float* __restrict__ fea,
                      const float* __restrict__ dw_w0, const float* __restrict__ dw_b0,
                      const float* __restrict__ pw_w, const float* __restrict__ pw_b,
                      const float* __restrict__ inputs,
                      const float* __restrict__ dcn_wt, const float* __restrict__ dcn_b,
                      float* __restrict__ outbuf) {
    __shared__ float lw[21 * 64];
    for (int i = threadIdx.x; i < 21 * 16; i += 256)
        ((float4*)lw)[i] = ((const float4*)pw_w)[i];
    __syncthreads();
    int gid = blockIdx.x;
    int b = gid / PIX_BLOCKS;
    int p = (gid % PIX_BLOCKS) * 256 + threadIdx.x;
    int h = p / WW, wq = p % WW;
    const float* inb = inputs + (size_t)b * NC * HWP;

    f32x16 dwv0, dwv1, dwv2, dwv3;
    {
        const float* fp = fea + (size_t)(b * CF) * HWP + p;
#pragma unroll
        for (int j = 0; j < 16; ++j) dwv0[j] = fp[(size_t)j * HWP] * dw_w0[j] + dw_b0[j];
#pragma unroll
        for (int j = 0; j < 16; ++j) dwv1[j] = fp[(size_t)(16 + j) * HWP] * dw_w0[16 + j] + dw_b0[16 + j];
#pragma unroll
        for (int j = 0; j < 16; ++j) dwv2[j] = fp[(size_t)(32 + j) * HWP] * dw_w0[32 + j] + dw_b0[32 + j];
#pragma unroll
        for (int j = 0; j < 16; ++j) dwv3[j] = fp[(size_t)(48 + j) * HWP] * dw_w0[48 + j] + dw_b0[48 + j];
    }
    f32x16 acc0, acc1, acc2, acc3;
#pragma unroll
    for (int j = 0; j < 16; ++j) { acc0[j] = 0.f; acc1[j] = 0.f; acc2[j] = 0.f; acc3[j] = 0.f; }

    for (int r = 0; r < NC; ++r) {
        const float* wy = lw + (2 * r) * 64;
        const float* wx = wy + 64;
        const float* wm = lw + (14 + r) * 64;
        const float* inc_ = inb + (size_t)r * HWP;
        float oy = pw_b[2 * r], ox = pw_b[2 * r + 1], om = pw_b[14 + r];
#pragma unroll
        for (int j = 0; j < 16; ++j) { oy += wy[j] * dwv0[j];      ox += wx[j] * dwv0[j];      om += wm[j] * dwv0[j]; }
#pragma unroll
        for (int j = 0; j < 16; ++j) { oy += wy[16 + j] * dwv1[j]; ox += wx[16 + j] * dwv1[j]; om += wm[16 + j] * dwv1[j]; }
#pragma unroll
        for (int j = 0; j < 16; ++j) { oy += wy[32 + j] * dwv2[j]; ox += wx[32 + j] * dwv2[j]; om += wm[32 + j] * dwv2[j]; }
#pragma unroll
        for (int j = 0; j < 16; ++j) { oy += wy[48 + j] * dwv3[j]; ox += wx[48 + j] * dwv3[j]; om += wm[48 + j] * dwv3[j]; }
        float m = 1.f / (1.f + __expf(-om));
        float py = oy + (float)h;
        float px = ox + (float)wq;
        float y0 = floorf(py), x0 = floorf(px);
        float wyf = py - y0, wxf = px - x0;
        int iy0 = (int)y0, ix0 = (int)x0;
        bool y0v = (iy0 >= 0) && (iy0 < HH);
        bool y1v = (iy0 + 1 >= 0) && (iy0 + 1 < HH);
        bool x0v = (ix0 >= 0) && (ix0 < WW);
        bool x1v = (ix0 + 1 >= 0) && (ix0 + 1 < WW);
        int yc0 = min(max(iy0, 0), HH - 1), yc1 = min(max(iy0 + 1, 0), HH - 1);
        int xc0 = min(max(ix0, 0), WW - 1), xc1 = min(max(ix0 + 1, 0), WW - 1);
        float v00 = 0.f, v01 = 0.f, v10 = 0.f, v11 = 0.f;
        if (y0v) {
            if (x0v) v00 = inc_[yc0 * WW + xc0];
            if (x1v) v01 = inc_[yc0 * WW + xc1];
        }
        if (y1v) {
            if (x0v) v10 = inc_[yc1 * WW + xc0];
            if (x1v) v11 = inc_[yc1 * WW + xc1];
        }
        float s = (v00 * (1.f - wyf) * (1.f - wxf) + v01 * (1.f - wyf) * wxf +
                   v10 * wyf * (1.f - wxf) + v11 * wyf * wxf) * m;
        const float* dt = dcn_wt + (size_t)r * OO;
#pragma unroll
        for (int j = 0; j < 16; ++j) acc0[j] += s * dt[j];
#pragma unroll
        for (int j = 0; j < 16; ++j) acc1[j] += s * dt[16 + j];
#pragma unroll
        for (int j = 0; j < 16; ++j) acc2[j] += s * dt[32 + j];
#pragma unroll
        for (int j = 0; j < 16; ++j) acc3[j] += s * dt[48 + j];
    }
    float* op = outbuf + (size_t)(b * 3 * OO) * HWP + p;
#pragma unroll
    for (int j = 0; j < 16; ++j) { float v = acc0[j] + dcn_b[j];      op[(size_t)j * HWP] = v > 0.f ? v : 0.f; }
#pragma unroll
    for (int j = 0; j < 16; ++j) { float v = acc1[j] + dcn_b[16 + j]; op[(size_t)(16 + j) * HWP] = v > 0.f ? v : 0.f; }
#pragma unroll
    for (int j = 0; j < 16; ++j) { float v = acc2[j] + dcn_b[32 + j]; op[(size_t)(32 + j) * HWP] = v > 0.f ? v : 0.f; }
#pragma unroll
    for (int j = 0; j < 16; ++j) { float v = acc3[j] + dcn_b[48 + j]; op[(size_t)(48 + j) * HWP] = v > 0.f ? v : 0.f; }
}

// ---------------- attention GEMM, KC=32 LDS chunks ------------------------
__global__ __launch_bounds__(256)
void attn_gemm_kernel(const float* __restrict__ outbuf, const float* __restrict__ attn_wt,
                      const float* __restrict__ attn_b, float* __restrict__ partial) {
    __shared__ float As[32][68];
    __shared__ float Bs[32][132];
    __shared__ float red[16][68];
    int nb0 = blockIdx.x * 128;
    int b = nb0 / HWP, p0 = nb0 % HWP;
    int tid = threadIdx.x;
    int tm = (tid & 15) * 4;
    int tn = (tid >> 4) * 8;

    f32x4 aA0 = 0.f, aA1 = 0.f, aB0 = 0.f, aB1 = 0.f;
    f32x4 aC0 = 0.f, aC1 = 0.f, aD0 = 0.f, aD1 = 0.f;
    for (int kc = 0; kc < 6; ++kc) {
        for (int i4 = tid; i4 < 32 * 16; i4 += 256) {
            int row = i4 >> 4, c4 = (i4 & 15) * 4;
            float4 v = *(const float4*)(attn_wt + (size_t)(kc * 32 + row) * OO + c4);
            As[row][c4] = v.x; As[row][c4 + 1] = v.y; As[row][c4 + 2] = v.z; As[row][c4 + 3] = v.w;
        }
        const float* bp = outbuf + ((size_t)(b * 192 + kc * 32)) * HWP + p0;
        for (int i4 = tid; i4 < 32 * 32; i4 += 256) {
            int row = i4 >> 5, f4 = (i4 & 31) * 4;
            float4 v = *(const float4*)(bp + (size_t)row * HWP + f4);
            *(float4*)&Bs[row][f4] = v;
        }
        __syncthreads();
#pragma unroll 4
        for (int kk = 0; kk < 32; ++kk) {
            f32x4 a  = *(const f32x4*)&As[kk][tm];
            f32x4 b0 = *(const f32x4*)&Bs[kk][tn];
            f32x4 b1 = *(const f32x4*)&Bs[kk][tn + 4];
#pragma unroll
            for (int j = 0; j < 4; ++j) {
                aA0[j] += a[0] * b0[j];  aA1[j] += a[0] * b1[j];
                aB0[j] += a[1] * b0[j];  aB1[j] += a[1] * b1[j];
                aC0[j] += a[2] * b0[j];  aC1[j] += a[2] * b1[j];
                aD0[j] += a[3] * b0[j];  aD1[j] += a[3] * b1[j];
            }
        }
        __syncthreads();
    }
    float bsum[4];
    {
        f32x4 accs[8] = {aA0, aA1, aB0, aB1, aC0, aC1, aD0, aD1};
#pragma unroll
        for (int row = 0; row < 4; ++row) {
            float bi = attn_b[tm + row];
            float s = 0.f;
#pragma unroll
            for (int j = 0; j < 4; ++j) {
                float v0 = accs[row * 2][j] + bi;
                float v1 = accs[row * 2 + 1][j] + bi;
                s += (v0 > 0.f ? v0 : 0.f) + (v1 > 0.f ? v1 : 0.f);
            }
            bsum[row] = s;
        }
    }
    int pg = tid >> 4;
#pragma unroll
    for (int row = 0; row < 4; ++row) red[pg][tm + row] = bsum[row];
    __syncthreads();
    if (tid < 64) {
        float s = 0.f;
#pragma unroll
        for (int g = 0; g < 16; ++g) s += red[g][tid];
        int lb = p0 / 128;
        partial[((size_t)(b * PBLK2 + lb)) * OO + tid] = s;
    }
}

// ---------------- attention finish ----------------
__global__ void attn_finish_kernel(const float* __restrict__ partial,
                                   const float* __restrict__ fc_w, const float* __restrict__ fc_b,
                                   const float* __restrict__ fcs_w0, const float* __restrict__ fcs_b0,
                                   const float* __restrict__ fcs_w1, const float* __restrict__ fcs_b1,
                                   const float* __restrict__ fcs_w2, const float* __restrict__ fcs_b2,
                                   float* __restrict__ atts) {
    int b = blockIdx.x;
    __shared__ float attm[OO];
    __shared__ float fcv[32];
    int tid = threadIdx.x;
    if (tid < OO) {
        float s = 0.f;
        for (int blk = 0; blk < PBLK2; ++blk)
            s += partial[((size_t)(b * PBLK2 + blk)) * OO + tid];
        attm[tid] = s / (float)HWP;
    }
    __syncthreads();
    if (tid < 32) {
        float s = fc_b[tid];
        for (int o = 0; o < OO; ++o) s += fc_w[tid * OO + o] * attm[o];
        fcv[tid] = s > 0.f ? s : 0.f;
    }
    __syncthreads();
    if (tid < OO) {
        {
            float s = fcs_b0[tid];
            for (int j = 0; j < 32; ++j) s += fcs_w0[tid * 32 + j] * fcv[j];
            atts[b * 192 + 0 * OO + tid] = s;
        }
        {
            float s = fcs_b1[tid];
            for (int j = 0; j < 32; ++j) s += fcs_w1[tid * 32 + j] * fcv[j];
            atts[b * 192 + 1 * OO + tid] = s;
        }
        {
            float s = fcs_b2[tid];
            for (int j = 0; j < 32; ++j) s += fcs_w2[tid * 32 + j] * fcv[j];
            atts[b * 192 + 2 * OO + tid] = s;
        }
    }
}

// ---------------- final GEMM, KC=32 LDS chunks ----------------------------
__global__ __launch_bounds__(256)
void final_gemm_kernel(const float* __restrict__ outbuf, const float* __restrict__ atts,
                       const float* __restrict__ conv_wt, const float* __restrict__ conv_b,
                       float* __restrict__ out) {
    __shared__ float As[32][68];
    __shared__ float Bs[32][132];
    int nb0 = blockIdx.x * 128;
    int b = nb0 / HWP, p0 = nb0 % HWP;
    int tid = threadIdx.x;
    int tm = (tid & 15) * 4;
    int tn = (tid >> 4) * 8;
    const float* at = atts + b * 192;

    f32x4 aA0 = 0.f, aA1 = 0.f, aB0 = 0.f, aB1 = 0.f;
    f32x4 aC0 = 0.f, aC1 = 0.f, aD0 = 0.f, aD1 = 0.f;
    for (int kc = 0; kc < 6; ++kc) {
        for (int i4 = tid; i4 < 32 * 16; i4 += 256) {
            int row = i4 >> 4, c4 = (i4 & 15) * 4;
            float4 v = *(const float4*)(conv_wt + (size_t)(kc * 32 + row) * OO + c4);
            As[row][c4] = v.x; As[row][c4 + 1] = v.y; As[row][c4 + 2] = v.z; As[row][c4 + 3] = v.w;
        }
        const float* bp = outbuf + ((size_t)(b * 192 + kc * 32)) * HWP + p0;
        for (int i4 = tid; i4 < 32 * 32; i4 += 256) {
            int row = i4 >> 5, f4 = (i4 & 31) * 4;
            float sc = at[kc * 32 + row];
            float4 v = *(const float4*)(bp + (size_t)row * HWP + f4);
            Bs[row][f4] = v.x * sc; Bs[row][f4 + 1] = v.y * sc;
            Bs[row][f4 + 2] = v.z * sc; Bs[row][f4 + 3] = v.w * sc;
        }
        __syncthreads();
#pragma unroll 4
        for (int kk = 0; kk < 32; ++kk) {
            f32x4 a  = *(const f32x4*)&As[kk][tm];
            f32x4 b0 = *(const f32x4*)&Bs[kk][tn];
            f32x4 b1 = *(const f32x4*)&Bs[kk][tn + 4];
#pragma unroll
            for (int j = 0; j < 4; ++j) {
                aA0[j] += a[0] * b0[j];  aA1[j] += a[0] * b1[j];
                aB0[j] += a[1] * b0[j];  aB1[j] += a[1] * b1[j];
                aC0[j] += a[2] * b0[j];  aC1[j] += a[2] * b1[j];
                aD0[j] += a[3] * b0[j];  aD1[j] += a[3] * b1[j];
            }
        }
        __syncthreads();
    }
    f32x4 accs[8] = {aA0, aA1, aB0, aB1, aC0, aC1, aD0, aD1};
#pragma unroll
    for (int row = 0; row < 4; ++row) {
        int ch = tm + row;
        float bi = conv_b[ch];
        float* ptr = out + ((size_t)(b * OO + ch)) * HWP + p0 + tn;
        f32x4 lo = accs[row * 2], hi = accs[row * 2 + 1];
#pragma unroll
        for (int j = 0; j < 4; ++j) {
            lo[j] += bi; hi[j] += bi;
            lo[j] = lo[j] > 0.f ? lo[j] : 0.f;
            hi[j] = hi[j] > 0.f ? hi[j] : 0.f;
        }
        *(f32x4*)ptr = lo;
        *(f32x4*)(ptr + 4) = hi;
    }
}

extern "C" void kernel_launch(void* const* d_in, const int* in_sizes, int n_in,
                              void* d_out, int out_size, void* d_ws, size_t ws_size,
                              hipStream_t stream) {
    const float* fea    = (const float*)d_in[0];
    const float* inputs = (const float*)d_in[1];
    const float* dw_w[3]  = {(const float*)d_in[2],  (const float*)d_in[8],  (const float*)d_in[14]};
    const float* dw_b[3]  = {(const float*)d_in[3],  (const float*)d_in[9],  (const float*)d_in[15]};
    const float* pw_w[3]  = {(const float*)d_in[4],  (const float*)d_in[10], (const float*)d_in[16]};
    const float* pw_b[3]  = {(const float*)d_in[5],  (const float*)d_in[11], (const float*)d_in[17]};
    const float* dcn_w[3] = {(const float*)d_in[6],  (const float*)d_in[12], (const float*)d_in[18]};
    const float* dcn_b[3] = {(const float*)d_in[7],  (const float*)d_in[13], (const float*)d_in[19]};
    const float* attn_w = (const float*)d_in[20];
    const float* attn_b = (const float*)d_in[21];
    const float* fc_w   = (const float*)d_in[22];
    const float* fc_b   = (const float*)d_in[23];
    const float* fcs_w[3] = {(const float*)d_in[24], (const float*)d_in[26], (const float*)d_in[28]};
    const float* fcs_b[3] = {(const float*)d_in[25], (const float*)d_in[27], (const float*)d_in[29]};
    const float* conv_w = (const float*)d_in[30];
    const float* conv_b = (const float*)d_in[31];
    float* out = (float*)d_out;

    const size_t F_OUTBUF = (size_t)BB * 3 * OO * HWP;   // 28,311,552
    const size_t F_SMALL  = 73728 + 768 + 512 + 4096 + 11264 + 12288 + 12288 + 1344 + 32;
    float* W = (float*)d_ws;
    float* outbuf = W;            W += F_OUTBUF;
    size_t avail = (ws_size / 4 > F_OUTBUF + F_SMALL) ? (ws_size / 4 - F_OUTBUF - F_SMALL) : 0;
    int T = (int)(avail / (4 * (size_t)NTOT));   // om 3T rows + s T rows
    if (T > 64) T = 64;                          // acc_gemm LDS cap
    if (T < 1) T = 1;
    float* om = W;                W += (size_t)3 * T * NTOT;
    float* sbuf = W;              W += (size_t)T * NTOT;
    float* partial = W;           W += 73728;    // BB*PBLK2*64
    float* atts = W;              W += 768;
    float* dcn_wt0 = W;           W += 512;
    float* dcn_wt1 = W;           W += 4096;
    float* dcn_wt2 = W;           W += 11264;
    float* attn_wt = W;           W += 12288;
    float* conv_wt = W;           W += 12288;
    float* pw_wf = W;             W += 1344;     // folded k1 pw weights (21x64)
    float* pw_bf = W;             W += 32;       // folded k1 bias (21)
    float* dwscr = out;           // d_out as dw-plane scratch; final_gemm rewrites d_out

    transpose_kernel<<<(192 * 64 + 255) / 256, 256, 0, stream>>>(attn_w, attn_wt, 64, 192);
    transpose_kernel<<<(192 * 64 + 255) / 256, 256, 0, stream>>>(conv_w, conv_wt, 64, 192);
    transpose_kernel<<<(7 * 64 + 255) / 256, 256, 0, stream>>>(dcn_w[0], dcn_wt0, 64, 7);
    transpose_kernel<<<(63 * 64 + 255) / 256, 256, 0, stream>>>(dcn_w[1], dcn_wt1, 64, 63);
    transpose_kernel<<<(175 * 64 + 255) / 256, 256, 0, stream>>>(dcn_w[2], dcn_wt2, 64, 175);
    k1_fold_kernel<<<(21 * 64 + 255) / 256, 256, 0, stream>>>(pw_w[0], pw_b[0],
                                                              dw_w[0], dw_b[0], pw_wf, pw_bf);

    const int dwv_grid = (BB * CF * HH * 48) / 256;   // 9216
    const int pix_grid = BB * PIX_BLOCKS;             // 576
    const int samp_grid = 2 * (NTOT / 256);           // 1152
    const int acc_grid = NTOT / 128;                  // 1152
    const int ntiles = NTOT / 128;                    // 1152

    // ---- k=5 branch ----
    dwv_kernel<5><<<dwv_grid, 256, 0, stream>>>(fea, dw_w[2], dw_b[2], dwscr);
    {
        const int TT = 175;
        for (int t0 = 0; t0 < TT; t0 += T) {
            int t1 = (t0 + T < TT) ? (t0 + T) : TT;
            int Tc = t1 - t0, M = 3 * Tc;
            int mt = (M + 63) / 64;
            pw_gemm_kernel<<<mt * ntiles, 256, 0, stream>>>(pw_w[2], pw_b[2], dwscr, om,
                                                            2 * t0, 2 * Tc, 2 * TT + t0, M);
            sample_kernel<5><<<samp_grid, 256, 0, stream>>>(om, inputs, sbuf, t0, t1);
            int flags = (t0 == 0 ? 1 : 0) | (t1 == TT ? 2 : 0);
            acc_gemm_kernel<<<acc_grid, 256, 0, stream>>>(dcn_wt2, dcn_b[2], sbuf, outbuf,
                                                          2, t0, t1, flags);
        }
    }
    // ---- k=3 branch ----
    dwv_kernel<3><<<dwv_grid, 256, 0, stream>>>(fea, dw_w[1], dw_b[1], dwscr);
    {
        const int TT = 63;
        for (int t0 = 0; t0 < TT; t0 += T) {
            int t1 = (t0 + T < TT) ? (t0 + T) : TT;
            int Tc = t1 - t0, M = 3 * Tc;
            int mt = (M + 63) / 64;
            pw_gemm_kernel<<<mt * ntiles, 256, 0, stream>>>(pw_w[1], pw_b[1], dwscr, om,
                                                            2 * t0, 2 * Tc, 2 * TT + t0, M);
            sample_kernel<3><<<samp_grid, 256, 0, stream>>>(om, inputs, sbuf, t0, t1);
            int flags = (t0 == 0 ? 1 : 0) | (t1 == TT ? 2 : 0);
            acc_gemm_kernel<<<acc_grid, 256, 0, stream>>>(dcn_wt1, dcn_b[1], sbuf, outbuf,
                                                          1, t0, t1, flags);
        }
    }
    // ---- k=1 branch: folded pw GEMM on fea directly (no dw materialization)
    if (T >= 7) {
        pw_gemm_kernel<<<1 * ntiles, 256, 0, stream>>>(pw_wf, pw_bf, fea, om,
                                                       0, 14, 14, 21);
        sample_kernel<1><<<samp_grid, 256, 0, stream>>>(om, inputs, sbuf, 0, 7);
        acc_gemm_kernel<<<acc_grid, 256, 0, stream>>>(dcn_wt0, dcn_b[0], sbuf, outbuf,
                                                      0, 0, 7, 3);
    } else {
        branch_k1_kernel<<<pix_grid, 256, 0, stream>>>(fea, dw_w[0], dw_b[0], pw_w[0], pw_b[0],
                                                       inputs, dcn_wt0, dcn_b[0], outbuf);
    }

    // ---- attention + final (tiled GEMMs, KC=32) ----
    attn_gemm_kernel<<<NTOT / 128, 256, 0, stream>>>(outbuf, attn_wt, attn_b, partial);
    attn_finish_kernel<<<BB, 64, 0, stream>>>(partial, fc_w, fc_b,
                                              fcs_w[0], fcs_b[0], fcs_w[1], fcs_b[1],
                                              fcs_w[2], fcs_b[2], atts);
    final_gemm_kernel<<<NTOT / 128, 256, 0, stream>>>(outbuf, atts, conv_wt, conv_b, out);
}